// Round 1
// baseline (5038.134 us; speedup 1.0000x reference)
//
#include <hip/hip_runtime.h>
#include <hip/hip_bf16.h>

#define N_NODES 100000
#define N_EDGES 1600000
#define F_IN 512
#define H1 8
#define D1 8
#define F_MID 64   // H1*D1
#define C 16
#define NEG_SLOPE 0.2f

// ---------------- Layer 1: x @ W1 -> h1f [N,64], plus es1/ed1 [N,8] ----------------
// one wave per node row; x row staged in LDS; lane = output column
__global__ void k_gemm1(const float* __restrict__ x, const float* __restrict__ W1,
                        const float* __restrict__ a1s, const float* __restrict__ a1d,
                        float* __restrict__ h1f, float* __restrict__ es1,
                        float* __restrict__ ed1, int n_nodes) {
    __shared__ float xs[4][F_IN];
    const int wave = threadIdx.x >> 6;
    const int lane = threadIdx.x & 63;
    int n = blockIdx.x * 4 + wave;
    const int n_clamped = n < n_nodes ? n : (n_nodes - 1);

    // stage x row (512 floats = 128 float4) into LDS: 2 float4 per lane
    const float4* xrow = (const float4*)(x + (size_t)n_clamped * F_IN);
    float4* xsv = (float4*)xs[wave];
    xsv[lane] = xrow[lane];
    xsv[lane + 64] = xrow[lane + 64];
    __syncthreads();

    float acc = 0.f;
#pragma unroll 8
    for (int k = 0; k < F_IN; ++k)
        acc += xs[wave][k] * W1[k * F_MID + lane];

    // attention dots: head = lane>>3, d = lane&7; reduce over 8-lane groups
    float vs = acc * a1s[lane];
    float vd = acc * a1d[lane];
#pragma unroll
    for (int off = 1; off < 8; off <<= 1) {
        vs += __shfl_xor(vs, off, 64);
        vd += __shfl_xor(vd, off, 64);
    }
    if (n < n_nodes) {
        h1f[(size_t)n * F_MID + lane] = acc;
        if ((lane & 7) == 0) {
            es1[n * H1 + (lane >> 3)] = vs;
            ed1[n * H1 + (lane >> 3)] = vd;
        }
    }
}

// ---------------- Layer 1 edge pass: thread per (edge, head) ----------------
__global__ void k_edge1(const int* __restrict__ src, const int* __restrict__ dst,
                        const float* __restrict__ es1, const float* __restrict__ ed1,
                        const float* __restrict__ h1f, float* __restrict__ acc1,
                        float* __restrict__ den1, int n_edges) {
    int gid = blockIdx.x * blockDim.x + threadIdx.x;
    if (gid >= n_edges * H1) return;
    const int e = gid >> 3, h = gid & 7;
    const int s = src[e], d = dst[e];
    float ev = es1[s * H1 + h] + ed1[d * H1 + h];
    ev = ev > 0.f ? ev : NEG_SLOPE * ev;
    const float w = __expf(ev);
    atomicAdd(&den1[d * H1 + h], w);
    const float* hs = h1f + (size_t)s * F_MID + h * D1;
    float* ad = acc1 + (size_t)d * F_MID + h * D1;
#pragma unroll
    for (int j = 0; j < D1; ++j) atomicAdd(&ad[j], hs[j] * w);
}

// ---------------- Layer 1 finalize: add self-loop, divide, ELU (in-place into acc1) ----------------
__global__ void k_final1(const float* __restrict__ h1f, const float* __restrict__ es1,
                         const float* __restrict__ ed1, const float* __restrict__ den1,
                         float* __restrict__ acc1, int n_nodes) {
    int gid = blockIdx.x * blockDim.x + threadIdx.x;  // n*64 + c
    if (gid >= n_nodes * F_MID) return;
    const int n = gid >> 6, c = gid & 63, h = c >> 3;
    float ev = es1[n * H1 + h] + ed1[n * H1 + h];
    ev = ev > 0.f ? ev : NEG_SLOPE * ev;
    const float ws = __expf(ev);
    float v = (acc1[gid] + h1f[gid] * ws) / (den1[n * H1 + h] + ws);
    v = v > 0.f ? v : expm1f(v);  // ELU
    acc1[gid] = v;                // acc1 becomes h1
}

// ---------------- Layer 2 transform: h1[N,64] @ W2[64,16] + att dots ----------------
__global__ void k_gemm2(const float* __restrict__ h1, const float* __restrict__ W2,
                        const float* __restrict__ a2s, const float* __restrict__ a2d,
                        float* __restrict__ h2f, float* __restrict__ es2,
                        float* __restrict__ ed2, int n_nodes) {
    __shared__ float w2s[F_MID * C];    // 1024 floats
    __shared__ float h1s[16][F_MID + 1];  // +1 pad breaks 4-way bank conflict
    const int t = threadIdx.x;
    const int nb = blockIdx.x * 16;
    for (int i = t; i < F_MID * C; i += 256) w2s[i] = W2[i];
    for (int i = t; i < 16 * F_MID; i += 256) {
        int r = i >> 6, k = i & 63;
        int n = nb + r;
        h1s[r][k] = h1[(size_t)(n < n_nodes ? n : n_nodes - 1) * F_MID + k];
    }
    __syncthreads();
    const int r = t >> 4, c = t & 15;
    const int n = nb + r;
    float acc = 0.f;
#pragma unroll
    for (int k = 0; k < F_MID; ++k) acc += h1s[r][k] * w2s[k * C + c];
    float vs = acc * a2s[c], vd = acc * a2d[c];
#pragma unroll
    for (int off = 1; off < 16; off <<= 1) {
        vs += __shfl_xor(vs, off, 64);
        vd += __shfl_xor(vd, off, 64);
    }
    if (n < n_nodes) {
        h2f[(size_t)n * C + c] = acc;
        if (c == 0) { es2[n] = vs; ed2[n] = vd; }
    }
}

// ---------------- Layer 2 edge pass: thread per edge ----------------
__global__ void k_edge2(const int* __restrict__ src, const int* __restrict__ dst,
                        const float* __restrict__ es2, const float* __restrict__ ed2,
                        const float* __restrict__ h2f, float* __restrict__ acc2,
                        float* __restrict__ den2, int n_edges) {
    int e = blockIdx.x * blockDim.x + threadIdx.x;
    if (e >= n_edges) return;
    const int s = src[e], d = dst[e];
    float ev = es2[s] + ed2[d];
    ev = ev > 0.f ? ev : NEG_SLOPE * ev;
    const float w = __expf(ev);
    atomicAdd(&den2[d], w);
    const float* hs = h2f + (size_t)s * C;
    float* ad = acc2 + (size_t)d * C;
#pragma unroll
    for (int j = 0; j < C; ++j) atomicAdd(&ad[j], hs[j] * w);
}

// ---------------- Layer 2 finalize + log_softmax ----------------
__global__ void k_final2(const float* __restrict__ h2f, const float* __restrict__ es2,
                         const float* __restrict__ ed2, const float* __restrict__ den2,
                         const float* __restrict__ acc2, float* __restrict__ out,
                         int n_nodes) {
    int gid = blockIdx.x * blockDim.x + threadIdx.x;  // n*16 + c
    if (gid >= n_nodes * C) return;
    const int n = gid >> 4, c = gid & 15;
    float ev = es2[n] + ed2[n];
    ev = ev > 0.f ? ev : NEG_SLOPE * ev;
    const float ws = __expf(ev);
    float v = (acc2[gid] + h2f[gid] * ws) / (den2[n] + ws);
    // log_softmax across the 16 lanes of this node (lane groups align: 256 % 16 == 0)
    float m = v;
#pragma unroll
    for (int off = 1; off < 16; off <<= 1) m = fmaxf(m, __shfl_xor(m, off, 64));
    float se = __expf(v - m);
#pragma unroll
    for (int off = 1; off < 16; off <<= 1) se += __shfl_xor(se, off, 64);
    out[gid] = v - m - __logf(se);
}

extern "C" void kernel_launch(void* const* d_in, const int* in_sizes, int n_in,
                              void* d_out, int out_size, void* d_ws, size_t ws_size,
                              hipStream_t stream) {
    const float* x   = (const float*)d_in[0];
    const int*   ei  = (const int*)d_in[1];
    const float* W1  = (const float*)d_in[2];
    const float* a1s = (const float*)d_in[3];
    const float* a1d = (const float*)d_in[4];
    const float* W2  = (const float*)d_in[5];
    const float* a2s = (const float*)d_in[6];
    const float* a2d = (const float*)d_in[7];
    float* out = (float*)d_out;

    const int n_nodes = in_sizes[0] / F_IN;     // 100000
    const int n_edges = in_sizes[1] / 2;        // 1600000
    const int* src = ei;
    const int* dst = ei + n_edges;

    // workspace layout (floats)
    float* ws = (float*)d_ws;
    float* h1f  = ws;                              // N*64
    float* es1  = h1f  + (size_t)n_nodes * F_MID;  // N*8
    float* ed1  = es1  + (size_t)n_nodes * H1;     // N*8
    float* acc1 = ed1  + (size_t)n_nodes * H1;     // N*64  (zeroed)
    float* den1 = acc1 + (size_t)n_nodes * F_MID;  // N*8   (zeroed)
    float* h2f  = den1 + (size_t)n_nodes * H1;     // N*16
    float* es2  = h2f  + (size_t)n_nodes * C;      // N
    float* ed2  = es2  + (size_t)n_nodes;          // N
    float* acc2 = ed2  + (size_t)n_nodes;          // N*16  (zeroed)
    float* den2 = acc2 + (size_t)n_nodes * C;      // N     (zeroed)

    // zero the atomic accumulators (ws is poisoned 0xAA before every launch)
    hipMemsetAsync(acc1, 0, (size_t)n_nodes * (F_MID + H1) * sizeof(float), stream);
    hipMemsetAsync(acc2, 0, (size_t)n_nodes * (C + 1) * sizeof(float), stream);

    k_gemm1<<<(n_nodes + 3) / 4, 256, 0, stream>>>(x, W1, a1s, a1d, h1f, es1, ed1, n_nodes);
    k_edge1<<<(n_edges * H1 + 255) / 256, 256, 0, stream>>>(src, dst, es1, ed1, h1f, acc1, den1, n_edges);
    k_final1<<<(n_nodes * F_MID + 255) / 256, 256, 0, stream>>>(h1f, es1, ed1, den1, acc1, n_nodes);
    k_gemm2<<<(n_nodes + 15) / 16, 256, 0, stream>>>(acc1, W2, a2s, a2d, h2f, es2, ed2, n_nodes);
    k_edge2<<<(n_edges + 255) / 256, 256, 0, stream>>>(src, dst, es2, ed2, h2f, acc2, den2, n_edges);
    k_final2<<<(n_nodes * C + 255) / 256, 256, 0, stream>>>(h2f, es2, ed2, den2, acc2, out, n_nodes);
}

// Round 2
// 1023.315 us; speedup vs baseline: 4.9233x; 4.9233x over previous
//
#include <hip/hip_runtime.h>
#include <hip/hip_bf16.h>

#define F_IN 512
#define H1 8
#define D1 8
#define F_MID 64   // H1*D1
#define C 16
#define NEG_SLOPE 0.2f

// ============ counting-sort CSR build (by dst) ============
__global__ void k_hist(const int* __restrict__ dst, int* __restrict__ counts, int n_edges) {
    int e = blockIdx.x * blockDim.x + threadIdx.x;
    if (e < n_edges) atomicAdd(&counts[dst[e]], 1);
}

// single-block exclusive scan over counts[n] -> row_start[n+1], cursor[n]
__global__ __launch_bounds__(1024) void k_scan(const int* __restrict__ counts,
                                               int* __restrict__ row_start,
                                               int* __restrict__ cursor, int n) {
    __shared__ int sums[1024];
    const int t = threadIdx.x;
    const int chunk = (n + 1023) >> 10;
    int lo = t * chunk, hi = lo + chunk;
    if (lo > n) lo = n;
    if (hi > n) hi = n;
    int s = 0;
    for (int i = lo; i < hi; ++i) s += counts[i];
    sums[t] = s;
    __syncthreads();
    for (int d = 1; d < 1024; d <<= 1) {
        int v = (t >= d) ? sums[t - d] : 0;
        __syncthreads();
        sums[t] += v;
        __syncthreads();
    }
    int off = sums[t] - s;   // exclusive prefix
    for (int i = lo; i < hi; ++i) {
        int c = counts[i];
        row_start[i] = off;
        cursor[i] = off;
        off += c;
    }
    if (t == 1023) row_start[n] = sums[1023];
}

__global__ void k_scatter(const int* __restrict__ src, const int* __restrict__ dst,
                          int* __restrict__ cursor, int* __restrict__ sorted_src, int n_edges) {
    int e = blockIdx.x * blockDim.x + threadIdx.x;
    if (e >= n_edges) return;
    int pos = atomicAdd(&cursor[dst[e]], 1);
    sorted_src[pos] = src[e];
}

// ============ Layer 1 GEMM: x[N,512] @ W1[512,64] -> h1f[N,64] ============
// 64-row tile per block, K staged 64 at a time; xsT transposed in LDS; 4x4 reg tile.
__global__ __launch_bounds__(256) void k_gemm1(const float* __restrict__ x,
                                               const float* __restrict__ W1,
                                               float* __restrict__ h1f, int n_nodes) {
    __shared__ float xsT[64][65];   // [k][row], +1 pad
    __shared__ float wst[64][64];   // [k][col]
    const int t = threadIdx.x;
    const int rowbase = blockIdx.x * 64;
    const int tr = t >> 4, tc = t & 15;   // 16x16 thread grid, 4x4 regs each
    float acc[4][4] = {{0.f}};

    for (int kt = 0; kt < F_IN; kt += 64) {
#pragma unroll
        for (int i = 0; i < 4; ++i) {     // x tile: 64 rows x 64 k
            int r = i * 16 + (t >> 4);
            int gr = rowbase + r;
            gr = gr < n_nodes ? gr : n_nodes - 1;
            int k0 = (t & 15) * 4;
            float4 v = *(const float4*)(x + (size_t)gr * F_IN + kt + k0);
            xsT[k0 + 0][r] = v.x; xsT[k0 + 1][r] = v.y;
            xsT[k0 + 2][r] = v.z; xsT[k0 + 3][r] = v.w;
        }
#pragma unroll
        for (int i = 0; i < 4; ++i) {     // W tile: 64 k x 64 cols
            int k = i * 16 + (t >> 4);
            *(float4*)&wst[k][(t & 15) * 4] =
                *(const float4*)(W1 + (size_t)(kt + k) * F_MID + (t & 15) * 4);
        }
        __syncthreads();
#pragma unroll
        for (int k = 0; k < 64; ++k) {
            float4 xa = *(float4*)&xsT[k][tr * 4];
            float4 wb = *(float4*)&wst[k][tc * 4];
            acc[0][0] += xa.x * wb.x; acc[0][1] += xa.x * wb.y; acc[0][2] += xa.x * wb.z; acc[0][3] += xa.x * wb.w;
            acc[1][0] += xa.y * wb.x; acc[1][1] += xa.y * wb.y; acc[1][2] += xa.y * wb.z; acc[1][3] += xa.y * wb.w;
            acc[2][0] += xa.z * wb.x; acc[2][1] += xa.z * wb.y; acc[2][2] += xa.z * wb.z; acc[2][3] += xa.z * wb.w;
            acc[3][0] += xa.w * wb.x; acc[3][1] += xa.w * wb.y; acc[3][2] += xa.w * wb.z; acc[3][3] += xa.w * wb.w;
        }
        __syncthreads();
    }
#pragma unroll
    for (int i = 0; i < 4; ++i) {
        int row = rowbase + tr * 4 + i;
        if (row < n_nodes) {
            float4 v = make_float4(acc[i][0], acc[i][1], acc[i][2], acc[i][3]);
            *(float4*)(h1f + (size_t)row * F_MID + tc * 4) = v;
        }
    }
}

// ============ Layer 1 attention dots: es1/ed1 [N,8] ============
__global__ void k_att1(const float* __restrict__ h1f, const float* __restrict__ a1s,
                       const float* __restrict__ a1d, float* __restrict__ es1,
                       float* __restrict__ ed1, int n_nodes) {
    int gid = blockIdx.x * blockDim.x + threadIdx.x;  // n*8+h
    if (gid >= n_nodes * H1) return;
    const int h = gid & 7;
    const float4* hp = (const float4*)(h1f + (size_t)gid * D1);
    float4 v0 = hp[0], v1 = hp[1];
    const float4* as = (const float4*)(a1s + h * D1);
    const float4* ad = (const float4*)(a1d + h * D1);
    float4 s0 = as[0], s1 = as[1], d0 = ad[0], d1 = ad[1];
    es1[gid] = v0.x * s0.x + v0.y * s0.y + v0.z * s0.z + v0.w * s0.w +
               v1.x * s1.x + v1.y * s1.y + v1.z * s1.z + v1.w * s1.w;
    ed1[gid] = v0.x * d0.x + v0.y * d0.y + v0.z * d0.z + v0.w * d0.w +
               v1.x * d1.x + v1.y * d1.y + v1.z * d1.z + v1.w * d1.w;
}

// ============ Layer 1 gather: wave per node, lane = feature ============
__global__ __launch_bounds__(256) void k_gather1(const int* __restrict__ row_start,
                                                 const int* __restrict__ sorted_src,
                                                 const float* __restrict__ h1f,
                                                 const float* __restrict__ es1,
                                                 const float* __restrict__ ed1,
                                                 float* __restrict__ h1, int n_nodes) {
    const int n = blockIdx.x * 4 + (threadIdx.x >> 6);
    const int lane = threadIdx.x & 63;
    const int h = lane >> 3;
    const int nc = n < n_nodes ? n : n_nodes - 1;
    const float edh = ed1[nc * H1 + h];
    const int beg = row_start[nc], end = row_start[nc + 1];
    float acc = 0.f, den = 0.f;
    for (int e = beg; e < end; ++e) {
        const int s = sorted_src[e];
        float ev = es1[s * H1 + h] + edh;
        ev = ev > 0.f ? ev : NEG_SLOPE * ev;
        const float w = __expf(ev);
        acc += w * h1f[(size_t)s * F_MID + lane];
        den += w;
    }
    // self-loop
    float evs = es1[nc * H1 + h] + edh;
    evs = evs > 0.f ? evs : NEG_SLOPE * evs;
    const float ws = __expf(evs);
    acc += ws * h1f[(size_t)nc * F_MID + lane];
    den += ws;
    float v = acc / den;
    v = v > 0.f ? v : expm1f(v);   // ELU
    if (n < n_nodes) h1[(size_t)n * F_MID + lane] = v;
}

// ============ Layer 2 transform: h1[N,64] @ W2[64,16] + att dots ============
__global__ void k_gemm2(const float* __restrict__ h1, const float* __restrict__ W2,
                        const float* __restrict__ a2s, const float* __restrict__ a2d,
                        float* __restrict__ h2f, float* __restrict__ es2,
                        float* __restrict__ ed2, int n_nodes) {
    __shared__ float w2s[F_MID * C];      // 1024 floats
    __shared__ float h1s[16][F_MID + 1];
    const int t = threadIdx.x;
    const int nb = blockIdx.x * 16;
    for (int i = t; i < F_MID * C; i += 256) w2s[i] = W2[i];
    for (int i = t; i < 16 * F_MID; i += 256) {
        int r = i >> 6, k = i & 63;
        int n = nb + r;
        h1s[r][k] = h1[(size_t)(n < n_nodes ? n : n_nodes - 1) * F_MID + k];
    }
    __syncthreads();
    const int r = t >> 4, c = t & 15;
    const int n = nb + r;
    float acc = 0.f;
#pragma unroll
    for (int k = 0; k < F_MID; ++k) acc += h1s[r][k] * w2s[k * C + c];
    float vs = acc * a2s[c], vd = acc * a2d[c];
#pragma unroll
    for (int off = 1; off < 16; off <<= 1) {
        vs += __shfl_xor(vs, off, 64);
        vd += __shfl_xor(vd, off, 64);
    }
    if (n < n_nodes) {
        h2f[(size_t)n * C + c] = acc;
        if (c == 0) { es2[n] = vs; ed2[n] = vd; }
    }
}

// ============ Layer 2 gather + log_softmax: 16 lanes per node ============
__global__ __launch_bounds__(256) void k_gather2(const int* __restrict__ row_start,
                                                 const int* __restrict__ sorted_src,
                                                 const float* __restrict__ h2f,
                                                 const float* __restrict__ es2,
                                                 const float* __restrict__ ed2,
                                                 float* __restrict__ out, int n_nodes) {
    const int n = blockIdx.x * 16 + (threadIdx.x >> 4);
    const int c = threadIdx.x & 15;
    const int nc = n < n_nodes ? n : n_nodes - 1;
    const float ed = ed2[nc];
    const int beg = row_start[nc], end = row_start[nc + 1];
    float acc = 0.f, den = 0.f;
    for (int e = beg; e < end; ++e) {
        const int s = sorted_src[e];
        float ev = es2[s] + ed;
        ev = ev > 0.f ? ev : NEG_SLOPE * ev;
        const float w = __expf(ev);
        acc += w * h2f[(size_t)s * C + c];
        den += w;
    }
    float evs = es2[nc] + ed;
    evs = evs > 0.f ? evs : NEG_SLOPE * evs;
    const float ws = __expf(evs);
    acc += ws * h2f[(size_t)nc * C + c];
    den += ws;
    const float v = acc / den;
    // log_softmax across 16-lane group (xor with off<16 stays in group)
    float m = v;
#pragma unroll
    for (int off = 1; off < 16; off <<= 1) m = fmaxf(m, __shfl_xor(m, off, 64));
    float se = __expf(v - m);
#pragma unroll
    for (int off = 1; off < 16; off <<= 1) se += __shfl_xor(se, off, 64);
    if (n < n_nodes) out[(size_t)n * C + c] = v - m - __logf(se);
}

extern "C" void kernel_launch(void* const* d_in, const int* in_sizes, int n_in,
                              void* d_out, int out_size, void* d_ws, size_t ws_size,
                              hipStream_t stream) {
    const float* x   = (const float*)d_in[0];
    const int*   ei  = (const int*)d_in[1];
    const float* W1  = (const float*)d_in[2];
    const float* a1s = (const float*)d_in[3];
    const float* a1d = (const float*)d_in[4];
    const float* W2  = (const float*)d_in[5];
    const float* a2s = (const float*)d_in[6];
    const float* a2d = (const float*)d_in[7];
    float* out = (float*)d_out;

    const int n_nodes = in_sizes[0] / F_IN;   // 100000
    const int n_edges = in_sizes[1] / 2;      // 1600000
    const int* src = ei;
    const int* dst = ei + n_edges;

    // workspace layout
    float* fws = (float*)d_ws;
    float* h1f = fws;                                  // N*64
    float* es1 = h1f + (size_t)n_nodes * F_MID;        // N*8
    float* ed1 = es1 + (size_t)n_nodes * H1;           // N*8
    float* h1  = ed1 + (size_t)n_nodes * H1;           // N*64
    float* h2f = h1  + (size_t)n_nodes * F_MID;        // N*16
    float* es2 = h2f + (size_t)n_nodes * C;            // N
    float* ed2 = es2 + (size_t)n_nodes;                // N
    int* iws        = (int*)(ed2 + n_nodes);
    int* counts     = iws;                             // N   (zeroed)
    int* row_start  = counts + n_nodes;                // N+1
    int* cursor     = row_start + n_nodes + 1;         // N
    int* sorted_src = cursor + n_nodes;                // E

    hipMemsetAsync(counts, 0, (size_t)n_nodes * sizeof(int), stream);

    // CSR build (shared by both layers)
    k_hist<<<(n_edges + 255) / 256, 256, 0, stream>>>(dst, counts, n_edges);
    k_scan<<<1, 1024, 0, stream>>>(counts, row_start, cursor, n_nodes);
    k_scatter<<<(n_edges + 255) / 256, 256, 0, stream>>>(src, dst, cursor, sorted_src, n_edges);

    // Layer 1
    k_gemm1<<<(n_nodes + 63) / 64, 256, 0, stream>>>(x, W1, h1f, n_nodes);
    k_att1<<<(n_nodes * H1 + 255) / 256, 256, 0, stream>>>(h1f, a1s, a1d, es1, ed1, n_nodes);
    k_gather1<<<(n_nodes + 3) / 4, 256, 0, stream>>>(row_start, sorted_src, h1f, es1, ed1, h1, n_nodes);

    // Layer 2
    k_gemm2<<<(n_nodes + 15) / 16, 256, 0, stream>>>(h1, W2, a2s, a2d, h2f, es2, ed2, n_nodes);
    k_gather2<<<(n_nodes + 15) / 16, 256, 0, stream>>>(row_start, sorted_src, h2f, es2, ed2, out, n_nodes);
}

// Round 3
// 814.910 us; speedup vs baseline: 6.1824x; 1.2557x over previous
//
#include <hip/hip_runtime.h>
#include <hip/hip_bf16.h>

#define F_IN 512
#define H1 8
#define D1 8
#define F_MID 64   // H1*D1
#define C 16
#define NEG_SLOPE 0.2f
#define SCAN_CHUNK 1024   // elements per block in the device-wide scan

// ============ counting-sort CSR build (by dst) ============
__global__ void k_hist(const int* __restrict__ dst, int* __restrict__ counts, int n_edges) {
    int e = blockIdx.x * blockDim.x + threadIdx.x;
    if (e < n_edges) atomicAdd(&counts[dst[e]], 1);
}

// ---- scan phase 1: per-block reduce of 1024-element chunks ----
__global__ __launch_bounds__(256) void k_scan_reduce(const int* __restrict__ counts,
                                                     int* __restrict__ block_sums, int n) {
    const int t = threadIdx.x;
    const int base = blockIdx.x * SCAN_CHUNK + t * 4;
    int s = 0;
#pragma unroll
    for (int j = 0; j < 4; ++j) {
        int idx = base + j;
        if (idx < n) s += counts[idx];
    }
#pragma unroll
    for (int off = 1; off < 64; off <<= 1) s += __shfl_xor(s, off, 64);
    __shared__ int ws[4];
    if ((t & 63) == 0) ws[t >> 6] = s;
    __syncthreads();
    if (t == 0) block_sums[blockIdx.x] = ws[0] + ws[1] + ws[2] + ws[3];
}

// ---- scan phase 2: single small block scans the block sums (nb <= 256) ----
__global__ __launch_bounds__(256) void k_scan_sums(int* __restrict__ block_sums,
                                                   int* __restrict__ block_offs,
                                                   int* __restrict__ row_start_last,
                                                   int nb) {
    __shared__ int sh[256];
    const int t = threadIdx.x;
    sh[t] = (t < nb) ? block_sums[t] : 0;
    __syncthreads();
#pragma unroll
    for (int d = 1; d < 256; d <<= 1) {
        int v = (t >= d) ? sh[t - d] : 0;
        __syncthreads();
        sh[t] += v;
        __syncthreads();
    }
    if (t < nb) block_offs[t] = sh[t] - block_sums[t];  // exclusive
    if (t == 255) *row_start_last = sh[255];            // total edge count
}

// ---- scan phase 3: local exclusive scan + global offset ----
__global__ __launch_bounds__(256) void k_scan_apply(const int* __restrict__ counts,
                                                    const int* __restrict__ block_offs,
                                                    int* __restrict__ row_start,
                                                    int* __restrict__ cursor, int n) {
    const int t = threadIdx.x;
    const int base = blockIdx.x * SCAN_CHUNK + t * 4;
    int c[4];
#pragma unroll
    for (int j = 0; j < 4; ++j) c[j] = (base + j < n) ? counts[base + j] : 0;
    const int tsum = c[0] + c[1] + c[2] + c[3];
    // wave-level inclusive scan of tsum
    int isc = tsum;
#pragma unroll
    for (int off = 1; off < 64; off <<= 1) {
        int v = __shfl_up(isc, off, 64);
        if ((t & 63) >= off) isc += v;
    }
    __shared__ int wsum[4];
    if ((t & 63) == 63) wsum[t >> 6] = isc;
    __syncthreads();
    int woff = 0;
    const int w = t >> 6;
    for (int i = 0; i < 4; ++i) if (i < w) woff += wsum[i];
    int off = block_offs[blockIdx.x] + woff + (isc - tsum);  // exclusive prefix for this thread
#pragma unroll
    for (int j = 0; j < 4; ++j) {
        int idx = base + j;
        if (idx < n) { row_start[idx] = off; cursor[idx] = off; }
        off += c[j];
    }
}

__global__ void k_scatter(const int* __restrict__ src, const int* __restrict__ dst,
                          int* __restrict__ cursor, int* __restrict__ sorted_src, int n_edges) {
    int e = blockIdx.x * blockDim.x + threadIdx.x;
    if (e >= n_edges) return;
    int pos = atomicAdd(&cursor[dst[e]], 1);
    sorted_src[pos] = src[e];
}

// ============ Layer 1 GEMM: x[N,512] @ W1[512,64] -> h1f[N,64] ============
__global__ __launch_bounds__(256) void k_gemm1(const float* __restrict__ x,
                                               const float* __restrict__ W1,
                                               float* __restrict__ h1f, int n_nodes) {
    __shared__ float xsT[64][65];   // [k][row], +1 pad
    __shared__ float wst[64][64];   // [k][col]
    const int t = threadIdx.x;
    const int rowbase = blockIdx.x * 64;
    const int tr = t >> 4, tc = t & 15;   // 16x16 thread grid, 4x4 regs each
    float acc[4][4] = {{0.f}};

    for (int kt = 0; kt < F_IN; kt += 64) {
#pragma unroll
        for (int i = 0; i < 4; ++i) {     // x tile: 64 rows x 64 k
            int r = i * 16 + (t >> 4);
            int gr = rowbase + r;
            gr = gr < n_nodes ? gr : n_nodes - 1;
            int k0 = (t & 15) * 4;
            float4 v = *(const float4*)(x + (size_t)gr * F_IN + kt + k0);
            xsT[k0 + 0][r] = v.x; xsT[k0 + 1][r] = v.y;
            xsT[k0 + 2][r] = v.z; xsT[k0 + 3][r] = v.w;
        }
#pragma unroll
        for (int i = 0; i < 4; ++i) {     // W tile: 64 k x 64 cols
            int k = i * 16 + (t >> 4);
            *(float4*)&wst[k][(t & 15) * 4] =
                *(const float4*)(W1 + (size_t)(kt + k) * F_MID + (t & 15) * 4);
        }
        __syncthreads();
#pragma unroll
        for (int k = 0; k < 64; ++k) {
            float4 xa = *(float4*)&xsT[k][tr * 4];
            float4 wb = *(float4*)&wst[k][tc * 4];
            acc[0][0] += xa.x * wb.x; acc[0][1] += xa.x * wb.y; acc[0][2] += xa.x * wb.z; acc[0][3] += xa.x * wb.w;
            acc[1][0] += xa.y * wb.x; acc[1][1] += xa.y * wb.y; acc[1][2] += xa.y * wb.z; acc[1][3] += xa.y * wb.w;
            acc[2][0] += xa.z * wb.x; acc[2][1] += xa.z * wb.y; acc[2][2] += xa.z * wb.z; acc[2][3] += xa.z * wb.w;
            acc[3][0] += xa.w * wb.x; acc[3][1] += xa.w * wb.y; acc[3][2] += xa.w * wb.z; acc[3][3] += xa.w * wb.w;
        }
        __syncthreads();
    }
#pragma unroll
    for (int i = 0; i < 4; ++i) {
        int row = rowbase + tr * 4 + i;
        if (row < n_nodes) {
            float4 v = make_float4(acc[i][0], acc[i][1], acc[i][2], acc[i][3]);
            *(float4*)(h1f + (size_t)row * F_MID + tc * 4) = v;
        }
    }
}

// ============ Layer 1 attention dots: es1/ed1 [N,8] ============
__global__ void k_att1(const float* __restrict__ h1f, const float* __restrict__ a1s,
                       const float* __restrict__ a1d, float* __restrict__ es1,
                       float* __restrict__ ed1, int n_nodes) {
    int gid = blockIdx.x * blockDim.x + threadIdx.x;  // n*8+h
    if (gid >= n_nodes * H1) return;
    const int h = gid & 7;
    const float4* hp = (const float4*)(h1f + (size_t)gid * D1);
    float4 v0 = hp[0], v1 = hp[1];
    const float4* as = (const float4*)(a1s + h * D1);
    const float4* ad = (const float4*)(a1d + h * D1);
    float4 s0 = as[0], s1 = as[1], d0 = ad[0], d1 = ad[1];
    es1[gid] = v0.x * s0.x + v0.y * s0.y + v0.z * s0.z + v0.w * s0.w +
               v1.x * s1.x + v1.y * s1.y + v1.z * s1.z + v1.w * s1.w;
    ed1[gid] = v0.x * d0.x + v0.y * d0.y + v0.z * d0.z + v0.w * d0.w +
               v1.x * d1.x + v1.y * d1.y + v1.z * d1.z + v1.w * d1.w;
}

// ============ Layer 1 gather: wave per node, lane = feature ============
__global__ __launch_bounds__(256) void k_gather1(const int* __restrict__ row_start,
                                                 const int* __restrict__ sorted_src,
                                                 const float* __restrict__ h1f,
                                                 const float* __restrict__ es1,
                                                 const float* __restrict__ ed1,
                                                 float* __restrict__ h1, int n_nodes) {
    const int n = blockIdx.x * 4 + (threadIdx.x >> 6);
    const int lane = threadIdx.x & 63;
    const int h = lane >> 3;
    const int nc = n < n_nodes ? n : n_nodes - 1;
    const float edh = ed1[nc * H1 + h];
    const int beg = row_start[nc], end = row_start[nc + 1];
    float acc = 0.f, den = 0.f;
    for (int e = beg; e < end; ++e) {
        const int s = sorted_src[e];
        float ev = es1[s * H1 + h] + edh;
        ev = ev > 0.f ? ev : NEG_SLOPE * ev;
        const float w = __expf(ev);
        acc += w * h1f[(size_t)s * F_MID + lane];
        den += w;
    }
    // self-loop
    float evs = es1[nc * H1 + h] + edh;
    evs = evs > 0.f ? evs : NEG_SLOPE * evs;
    const float ws = __expf(evs);
    acc += ws * h1f[(size_t)nc * F_MID + lane];
    den += ws;
    float v = acc / den;
    v = v > 0.f ? v : expm1f(v);   // ELU
    if (n < n_nodes) h1[(size_t)n * F_MID + lane] = v;
}

// ============ Layer 2 transform: h1[N,64] @ W2[64,16] + att dots ============
__global__ void k_gemm2(const float* __restrict__ h1, const float* __restrict__ W2,
                        const float* __restrict__ a2s, const float* __restrict__ a2d,
                        float* __restrict__ h2f, float* __restrict__ es2,
                        float* __restrict__ ed2, int n_nodes) {
    __shared__ float w2s[F_MID * C];      // 1024 floats
    __shared__ float h1s[16][F_MID + 1];
    const int t = threadIdx.x;
    const int nb = blockIdx.x * 16;
    for (int i = t; i < F_MID * C; i += 256) w2s[i] = W2[i];
    for (int i = t; i < 16 * F_MID; i += 256) {
        int r = i >> 6, k = i & 63;
        int n = nb + r;
        h1s[r][k] = h1[(size_t)(n < n_nodes ? n : n_nodes - 1) * F_MID + k];
    }
    __syncthreads();
    const int r = t >> 4, c = t & 15;
    const int n = nb + r;
    float acc = 0.f;
#pragma unroll
    for (int k = 0; k < F_MID; ++k) acc += h1s[r][k] * w2s[k * C + c];
    float vs = acc * a2s[c], vd = acc * a2d[c];
#pragma unroll
    for (int off = 1; off < 16; off <<= 1) {
        vs += __shfl_xor(vs, off, 64);
        vd += __shfl_xor(vd, off, 64);
    }
    if (n < n_nodes) {
        h2f[(size_t)n * C + c] = acc;
        if (c == 0) { es2[n] = vs; ed2[n] = vd; }
    }
}

// ============ Layer 2 gather + log_softmax: 16 lanes per node ============
__global__ __launch_bounds__(256) void k_gather2(const int* __restrict__ row_start,
                                                 const int* __restrict__ sorted_src,
                                                 const float* __restrict__ h2f,
                                                 const float* __restrict__ es2,
                                                 const float* __restrict__ ed2,
                                                 float* __restrict__ out, int n_nodes) {
    const int n = blockIdx.x * 16 + (threadIdx.x >> 4);
    const int c = threadIdx.x & 15;
    const int nc = n < n_nodes ? n : n_nodes - 1;
    const float ed = ed2[nc];
    const int beg = row_start[nc], end = row_start[nc + 1];
    float acc = 0.f, den = 0.f;
    for (int e = beg; e < end; ++e) {
        const int s = sorted_src[e];
        float ev = es2[s] + ed;
        ev = ev > 0.f ? ev : NEG_SLOPE * ev;
        const float w = __expf(ev);
        acc += w * h2f[(size_t)s * C + c];
        den += w;
    }
    float evs = es2[nc] + ed;
    evs = evs > 0.f ? evs : NEG_SLOPE * evs;
    const float ws = __expf(evs);
    acc += ws * h2f[(size_t)nc * C + c];
    den += ws;
    const float v = acc / den;
    float m = v;
#pragma unroll
    for (int off = 1; off < 16; off <<= 1) m = fmaxf(m, __shfl_xor(m, off, 64));
    float se = __expf(v - m);
#pragma unroll
    for (int off = 1; off < 16; off <<= 1) se += __shfl_xor(se, off, 64);
    if (n < n_nodes) out[(size_t)n * C + c] = v - m - __logf(se);
}

extern "C" void kernel_launch(void* const* d_in, const int* in_sizes, int n_in,
                              void* d_out, int out_size, void* d_ws, size_t ws_size,
                              hipStream_t stream) {
    const float* x   = (const float*)d_in[0];
    const int*   ei  = (const int*)d_in[1];
    const float* W1  = (const float*)d_in[2];
    const float* a1s = (const float*)d_in[3];
    const float* a1d = (const float*)d_in[4];
    const float* W2  = (const float*)d_in[5];
    const float* a2s = (const float*)d_in[6];
    const float* a2d = (const float*)d_in[7];
    float* out = (float*)d_out;

    const int n_nodes = in_sizes[0] / F_IN;   // 100000
    const int n_edges = in_sizes[1] / 2;      // 1600000
    const int* src = ei;
    const int* dst = ei + n_edges;
    const int n_scan_blocks = (n_nodes + SCAN_CHUNK - 1) / SCAN_CHUNK;   // 98 (<256)

    // workspace layout
    float* fws = (float*)d_ws;
    float* h1f = fws;                                  // N*64
    float* es1 = h1f + (size_t)n_nodes * F_MID;        // N*8
    float* ed1 = es1 + (size_t)n_nodes * H1;           // N*8
    float* h1  = ed1 + (size_t)n_nodes * H1;           // N*64
    float* h2f = h1  + (size_t)n_nodes * F_MID;        // N*16
    float* es2 = h2f + (size_t)n_nodes * C;            // N
    float* ed2 = es2 + (size_t)n_nodes;                // N
    int* iws        = (int*)(ed2 + n_nodes);
    int* counts     = iws;                             // N   (zeroed)
    int* row_start  = counts + n_nodes;                // N+1
    int* cursor     = row_start + n_nodes + 1;         // N
    int* sorted_src = cursor + n_nodes;                // E
    int* block_sums = sorted_src + n_edges;            // 256
    int* block_offs = block_sums + 256;                // 256

    hipMemsetAsync(counts, 0, (size_t)n_nodes * sizeof(int), stream);

    // CSR build (shared by both layers)
    k_hist<<<(n_edges + 255) / 256, 256, 0, stream>>>(dst, counts, n_edges);
    k_scan_reduce<<<n_scan_blocks, 256, 0, stream>>>(counts, block_sums, n_nodes);
    k_scan_sums<<<1, 256, 0, stream>>>(block_sums, block_offs, &row_start[n_nodes], n_scan_blocks);
    k_scan_apply<<<n_scan_blocks, 256, 0, stream>>>(counts, block_offs, row_start, cursor, n_nodes);
    k_scatter<<<(n_edges + 255) / 256, 256, 0, stream>>>(src, dst, cursor, sorted_src, n_edges);

    // Layer 1
    k_gemm1<<<(n_nodes + 63) / 64, 256, 0, stream>>>(x, W1, h1f, n_nodes);
    k_att1<<<(n_nodes * H1 + 255) / 256, 256, 0, stream>>>(h1f, a1s, a1d, es1, ed1, n_nodes);
    k_gather1<<<(n_nodes + 3) / 4, 256, 0, stream>>>(row_start, sorted_src, h1f, es1, ed1, h1, n_nodes);

    // Layer 2
    k_gemm2<<<(n_nodes + 15) / 16, 256, 0, stream>>>(h1, W2, a2s, a2d, h2f, es2, ed2, n_nodes);
    k_gather2<<<(n_nodes + 15) / 16, 256, 0, stream>>>(row_start, sorted_src, h2f, es2, ed2, out, n_nodes);
}

// Round 4
// 665.860 us; speedup vs baseline: 7.5664x; 1.2238x over previous
//
#include <hip/hip_runtime.h>
#include <hip/hip_bf16.h>

#define F_IN 512
#define H1 8
#define D1 8
#define F_MID 64   // H1*D1
#define C 16
#define NEG_SLOPE 0.2f
#define SCAN_CHUNK 1024

// ============ counting-sort CSR build (by dst) ============
__global__ void k_hist(const int* __restrict__ dst, int* __restrict__ counts, int n_edges) {
    int e = blockIdx.x * blockDim.x + threadIdx.x;
    if (e < n_edges) atomicAdd(&counts[dst[e]], 1);
}

__global__ __launch_bounds__(256) void k_scan_reduce(const int* __restrict__ counts,
                                                     int* __restrict__ block_sums, int n) {
    const int t = threadIdx.x;
    const int base = blockIdx.x * SCAN_CHUNK + t * 4;
    int s = 0;
#pragma unroll
    for (int j = 0; j < 4; ++j) {
        int idx = base + j;
        if (idx < n) s += counts[idx];
    }
#pragma unroll
    for (int off = 1; off < 64; off <<= 1) s += __shfl_xor(s, off, 64);
    __shared__ int ws[4];
    if ((t & 63) == 0) ws[t >> 6] = s;
    __syncthreads();
    if (t == 0) block_sums[blockIdx.x] = ws[0] + ws[1] + ws[2] + ws[3];
}

__global__ __launch_bounds__(256) void k_scan_sums(int* __restrict__ block_sums,
                                                   int* __restrict__ block_offs,
                                                   int* __restrict__ row_start_last,
                                                   int nb) {
    __shared__ int sh[256];
    const int t = threadIdx.x;
    sh[t] = (t < nb) ? block_sums[t] : 0;
    __syncthreads();
#pragma unroll
    for (int d = 1; d < 256; d <<= 1) {
        int v = (t >= d) ? sh[t - d] : 0;
        __syncthreads();
        sh[t] += v;
        __syncthreads();
    }
    if (t < nb) block_offs[t] = sh[t] - block_sums[t];
    if (t == 255) *row_start_last = sh[255];
}

__global__ __launch_bounds__(256) void k_scan_apply(const int* __restrict__ counts,
                                                    const int* __restrict__ block_offs,
                                                    int* __restrict__ row_start,
                                                    int* __restrict__ cursor, int n) {
    const int t = threadIdx.x;
    const int base = blockIdx.x * SCAN_CHUNK + t * 4;
    int c[4];
#pragma unroll
    for (int j = 0; j < 4; ++j) c[j] = (base + j < n) ? counts[base + j] : 0;
    const int tsum = c[0] + c[1] + c[2] + c[3];
    int isc = tsum;
#pragma unroll
    for (int off = 1; off < 64; off <<= 1) {
        int v = __shfl_up(isc, off, 64);
        if ((t & 63) >= off) isc += v;
    }
    __shared__ int wsum[4];
    if ((t & 63) == 63) wsum[t >> 6] = isc;
    __syncthreads();
    int woff = 0;
    const int w = t >> 6;
    for (int i = 0; i < 4; ++i) if (i < w) woff += wsum[i];
    int off = block_offs[blockIdx.x] + woff + (isc - tsum);
#pragma unroll
    for (int j = 0; j < 4; ++j) {
        int idx = base + j;
        if (idx < n) { row_start[idx] = off; cursor[idx] = off; }
        off += c[j];
    }
}

__global__ void k_scatter(const int* __restrict__ src, const int* __restrict__ dst,
                          int* __restrict__ cursor, int* __restrict__ sorted_src, int n_edges) {
    int e = blockIdx.x * blockDim.x + threadIdx.x;
    if (e >= n_edges) return;
    int pos = atomicAdd(&cursor[dst[e]], 1);
    sorted_src[pos] = src[e];
}

// ============ Layer 1 GEMM: x[N,512] @ W1[512,64] -> h1b (bf16) + es1/ed1 (fp32) ============
__global__ __launch_bounds__(256) void k_gemm1(const float* __restrict__ x,
                                               const float* __restrict__ W1,
                                               const float* __restrict__ a1s,
                                               const float* __restrict__ a1d,
                                               __hip_bfloat16* __restrict__ h1b,
                                               float* __restrict__ es1,
                                               float* __restrict__ ed1, int n_nodes) {
    __shared__ float xsT[64][65];
    __shared__ float wst[64][64];
    __shared__ float sas[64], sad[64];
    const int t = threadIdx.x;
    if (t < 64) sas[t] = a1s[t];
    else if (t < 128) sad[t - 64] = a1d[t - 64];
    const int rowbase = blockIdx.x * 64;
    const int tr = t >> 4, tc = t & 15;
    float acc[4][4] = {{0.f}};

    for (int kt = 0; kt < F_IN; kt += 64) {
#pragma unroll
        for (int i = 0; i < 4; ++i) {
            int r = i * 16 + (t >> 4);
            int gr = rowbase + r;
            gr = gr < n_nodes ? gr : n_nodes - 1;
            int k0 = (t & 15) * 4;
            float4 v = *(const float4*)(x + (size_t)gr * F_IN + kt + k0);
            xsT[k0 + 0][r] = v.x; xsT[k0 + 1][r] = v.y;
            xsT[k0 + 2][r] = v.z; xsT[k0 + 3][r] = v.w;
        }
#pragma unroll
        for (int i = 0; i < 4; ++i) {
            int k = i * 16 + (t >> 4);
            *(float4*)&wst[k][(t & 15) * 4] =
                *(const float4*)(W1 + (size_t)(kt + k) * F_MID + (t & 15) * 4);
        }
        __syncthreads();
#pragma unroll
        for (int k = 0; k < 64; ++k) {
            float4 xa = *(float4*)&xsT[k][tr * 4];
            float4 wb = *(float4*)&wst[k][tc * 4];
            acc[0][0] += xa.x * wb.x; acc[0][1] += xa.x * wb.y; acc[0][2] += xa.x * wb.z; acc[0][3] += xa.x * wb.w;
            acc[1][0] += xa.y * wb.x; acc[1][1] += xa.y * wb.y; acc[1][2] += xa.y * wb.z; acc[1][3] += xa.y * wb.w;
            acc[2][0] += xa.z * wb.x; acc[2][1] += xa.z * wb.y; acc[2][2] += xa.z * wb.z; acc[2][3] += xa.z * wb.w;
            acc[3][0] += xa.w * wb.x; acc[3][1] += xa.w * wb.y; acc[3][2] += xa.w * wb.z; acc[3][3] += xa.w * wb.w;
        }
        __syncthreads();
    }
    // epilogue: bf16 feature store + fused attention dots
    const int head = tc >> 1;     // each thread's 4 cols live in one head
#pragma unroll
    for (int i = 0; i < 4; ++i) {
        int row = rowbase + tr * 4 + i;
        float vs = acc[i][0] * sas[tc * 4 + 0] + acc[i][1] * sas[tc * 4 + 1] +
                   acc[i][2] * sas[tc * 4 + 2] + acc[i][3] * sas[tc * 4 + 3];
        float vd = acc[i][0] * sad[tc * 4 + 0] + acc[i][1] * sad[tc * 4 + 1] +
                   acc[i][2] * sad[tc * 4 + 2] + acc[i][3] * sad[tc * 4 + 3];
        vs += __shfl_xor(vs, 1, 64);   // combine the two half-head threads
        vd += __shfl_xor(vd, 1, 64);
        if (row < n_nodes) {
            __hip_bfloat16 b[4];
            b[0] = __float2bfloat16(acc[i][0]); b[1] = __float2bfloat16(acc[i][1]);
            b[2] = __float2bfloat16(acc[i][2]); b[3] = __float2bfloat16(acc[i][3]);
            *(ushort4*)(h1b + (size_t)row * F_MID + tc * 4) = *(ushort4*)b;
            if ((tc & 1) == 0) {
                es1[row * H1 + head] = vs;
                ed1[row * H1 + head] = vd;
            }
        }
    }
}

// ============ Layer 1 gather: wave per node, lane = feature, 4-wide edge unroll ============
__global__ __launch_bounds__(256) void k_gather1(const int* __restrict__ row_start,
                                                 const int* __restrict__ sorted_src,
                                                 const __hip_bfloat16* __restrict__ h1b,
                                                 const float* __restrict__ es1,
                                                 const float* __restrict__ ed1,
                                                 float* __restrict__ h1, int n_nodes) {
    const int n = blockIdx.x * 4 + (threadIdx.x >> 6);
    if (n >= n_nodes) return;
    const int lane = threadIdx.x & 63;
    const int h = lane >> 3;
    const float edh = ed1[n * H1 + h];
    const int beg = row_start[n], end = row_start[n + 1];
    float acc = 0.f, den = 0.f;
    for (int base = beg; base < end; base += 64) {
        const int m = min(64, end - base);
        const int li = lane < m ? lane : (m - 1);
        const int myS = sorted_src[base + li];
        int j = 0;
        for (; j + 4 <= m; j += 4) {
            const int s0 = __shfl(myS, j, 64), s1 = __shfl(myS, j + 1, 64);
            const int s2 = __shfl(myS, j + 2, 64), s3 = __shfl(myS, j + 3, 64);
            float e0 = es1[s0 * H1 + h], e1 = es1[s1 * H1 + h];
            float e2 = es1[s2 * H1 + h], e3 = es1[s3 * H1 + h];
            const float f0 = __bfloat162float(h1b[(size_t)s0 * F_MID + lane]);
            const float f1 = __bfloat162float(h1b[(size_t)s1 * F_MID + lane]);
            const float f2 = __bfloat162float(h1b[(size_t)s2 * F_MID + lane]);
            const float f3 = __bfloat162float(h1b[(size_t)s3 * F_MID + lane]);
            e0 += edh; e1 += edh; e2 += edh; e3 += edh;
            e0 = e0 > 0.f ? e0 : NEG_SLOPE * e0;
            e1 = e1 > 0.f ? e1 : NEG_SLOPE * e1;
            e2 = e2 > 0.f ? e2 : NEG_SLOPE * e2;
            e3 = e3 > 0.f ? e3 : NEG_SLOPE * e3;
            const float w0 = __expf(e0), w1 = __expf(e1), w2 = __expf(e2), w3 = __expf(e3);
            acc += w0 * f0 + w1 * f1 + w2 * f2 + w3 * f3;
            den += (w0 + w1) + (w2 + w3);
        }
        for (; j < m; ++j) {
            const int s = __shfl(myS, j, 64);
            float ev = es1[s * H1 + h] + edh;
            ev = ev > 0.f ? ev : NEG_SLOPE * ev;
            const float w = __expf(ev);
            acc += w * __bfloat162float(h1b[(size_t)s * F_MID + lane]);
            den += w;
        }
    }
    // self-loop
    float evs = es1[n * H1 + h] + edh;
    evs = evs > 0.f ? evs : NEG_SLOPE * evs;
    const float ws = __expf(evs);
    acc += ws * __bfloat162float(h1b[(size_t)n * F_MID + lane]);
    den += ws;
    float v = acc / den;
    v = v > 0.f ? v : expm1f(v);   // ELU
    h1[(size_t)n * F_MID + lane] = v;
}

// ============ Layer 2 transform: h1[N,64] @ W2[64,16] -> h2b (bf16) + es2/ed2 ============
__global__ void k_gemm2(const float* __restrict__ h1, const float* __restrict__ W2,
                        const float* __restrict__ a2s, const float* __restrict__ a2d,
                        __hip_bfloat16* __restrict__ h2b, float* __restrict__ es2,
                        float* __restrict__ ed2, int n_nodes) {
    __shared__ float w2s[F_MID * C];
    __shared__ float h1s[16][F_MID + 1];
    const int t = threadIdx.x;
    const int nb = blockIdx.x * 16;
    for (int i = t; i < F_MID * C; i += 256) w2s[i] = W2[i];
    for (int i = t; i < 16 * F_MID; i += 256) {
        int r = i >> 6, k = i & 63;
        int n = nb + r;
        h1s[r][k] = h1[(size_t)(n < n_nodes ? n : n_nodes - 1) * F_MID + k];
    }
    __syncthreads();
    const int r = t >> 4, c = t & 15;
    const int n = nb + r;
    float acc = 0.f;
#pragma unroll
    for (int k = 0; k < F_MID; ++k) acc += h1s[r][k] * w2s[k * C + c];
    float vs = acc * a2s[c], vd = acc * a2d[c];
#pragma unroll
    for (int off = 1; off < 16; off <<= 1) {
        vs += __shfl_xor(vs, off, 64);
        vd += __shfl_xor(vd, off, 64);
    }
    if (n < n_nodes) {
        h2b[(size_t)n * C + c] = __float2bfloat16(acc);
        if (c == 0) { es2[n] = vs; ed2[n] = vd; }
    }
}

// ============ Layer 2 gather + log_softmax: 16 lanes per node, 4-wide unroll ============
__global__ __launch_bounds__(256) void k_gather2(const int* __restrict__ row_start,
                                                 const int* __restrict__ sorted_src,
                                                 const __hip_bfloat16* __restrict__ h2b,
                                                 const float* __restrict__ es2,
                                                 const float* __restrict__ ed2,
                                                 float* __restrict__ out, int n_nodes) {
    const int n = blockIdx.x * 16 + (threadIdx.x >> 4);
    if (n >= n_nodes) return;
    const int lane = threadIdx.x & 63;
    const int c = lane & 15;
    const int g = lane >> 4;          // 16-lane group within the wave
    const float ed = ed2[n];
    const int beg = row_start[n], end = row_start[n + 1];
    float acc = 0.f, den = 0.f;
    for (int base = beg; base < end; base += 16) {
        const int m = min(16, end - base);
        const int li = c < m ? c : (m - 1);
        const int myS = sorted_src[base + li];
        int j = 0;
        for (; j + 4 <= m; j += 4) {
            const int s0 = __shfl(myS, g * 16 + j, 64), s1 = __shfl(myS, g * 16 + j + 1, 64);
            const int s2 = __shfl(myS, g * 16 + j + 2, 64), s3 = __shfl(myS, g * 16 + j + 3, 64);
            float e0 = es2[s0] + ed, e1 = es2[s1] + ed, e2 = es2[s2] + ed, e3 = es2[s3] + ed;
            const float f0 = __bfloat162float(h2b[(size_t)s0 * C + c]);
            const float f1 = __bfloat162float(h2b[(size_t)s1 * C + c]);
            const float f2 = __bfloat162float(h2b[(size_t)s2 * C + c]);
            const float f3 = __bfloat162float(h2b[(size_t)s3 * C + c]);
            e0 = e0 > 0.f ? e0 : NEG_SLOPE * e0;
            e1 = e1 > 0.f ? e1 : NEG_SLOPE * e1;
            e2 = e2 > 0.f ? e2 : NEG_SLOPE * e2;
            e3 = e3 > 0.f ? e3 : NEG_SLOPE * e3;
            const float w0 = __expf(e0), w1 = __expf(e1), w2 = __expf(e2), w3 = __expf(e3);
            acc += w0 * f0 + w1 * f1 + w2 * f2 + w3 * f3;
            den += (w0 + w1) + (w2 + w3);
        }
        for (; j < m; ++j) {
            const int s = __shfl(myS, g * 16 + j, 64);
            float ev = es2[s] + ed;
            ev = ev > 0.f ? ev : NEG_SLOPE * ev;
            const float w = __expf(ev);
            acc += w * __bfloat162float(h2b[(size_t)s * C + c]);
            den += w;
        }
    }
    float evs = es2[n] + ed;
    evs = evs > 0.f ? evs : NEG_SLOPE * evs;
    const float ws = __expf(evs);
    acc += ws * __bfloat162float(h2b[(size_t)n * C + c]);
    den += ws;
    const float v = acc / den;
    float mx = v;
#pragma unroll
    for (int off = 1; off < 16; off <<= 1) mx = fmaxf(mx, __shfl_xor(mx, off, 64));
    float se = __expf(v - mx);
#pragma unroll
    for (int off = 1; off < 16; off <<= 1) se += __shfl_xor(se, off, 64);
    out[(size_t)n * C + c] = v - mx - __logf(se);
}

extern "C" void kernel_launch(void* const* d_in, const int* in_sizes, int n_in,
                              void* d_out, int out_size, void* d_ws, size_t ws_size,
                              hipStream_t stream) {
    const float* x   = (const float*)d_in[0];
    const int*   ei  = (const int*)d_in[1];
    const float* W1  = (const float*)d_in[2];
    const float* a1s = (const float*)d_in[3];
    const float* a1d = (const float*)d_in[4];
    const float* W2  = (const float*)d_in[5];
    const float* a2s = (const float*)d_in[6];
    const float* a2d = (const float*)d_in[7];
    float* out = (float*)d_out;

    const int n_nodes = in_sizes[0] / F_IN;   // 100000
    const int n_edges = in_sizes[1] / 2;      // 1600000
    const int* src = ei;
    const int* dst = ei + n_edges;
    const int n_scan_blocks = (n_nodes + SCAN_CHUNK - 1) / SCAN_CHUNK;

    // workspace layout
    float* fws = (float*)d_ws;
    float* es1 = fws;                              // N*8
    float* ed1 = es1 + (size_t)n_nodes * H1;       // N*8
    float* h1  = ed1 + (size_t)n_nodes * H1;       // N*64
    float* es2 = h1  + (size_t)n_nodes * F_MID;    // N
    float* ed2 = es2 + n_nodes;                    // N
    __hip_bfloat16* h1b = (__hip_bfloat16*)(ed2 + n_nodes);   // N*64 bf16
    __hip_bfloat16* h2b = h1b + (size_t)n_nodes * F_MID;      // N*16 bf16
    int* iws        = (int*)(h2b + (size_t)n_nodes * C);
    int* counts     = iws;                         // N (zeroed)
    int* row_start  = counts + n_nodes;            // N+1
    int* cursor     = row_start + n_nodes + 1;     // N
    int* sorted_src = cursor + n_nodes;            // E
    int* block_sums = sorted_src + n_edges;        // 256
    int* block_offs = block_sums + 256;            // 256

    hipMemsetAsync(counts, 0, (size_t)n_nodes * sizeof(int), stream);

    // CSR build (shared by both layers)
    k_hist<<<(n_edges + 255) / 256, 256, 0, stream>>>(dst, counts, n_edges);
    k_scan_reduce<<<n_scan_blocks, 256, 0, stream>>>(counts, block_sums, n_nodes);
    k_scan_sums<<<1, 256, 0, stream>>>(block_sums, block_offs, &row_start[n_nodes], n_scan_blocks);
    k_scan_apply<<<n_scan_blocks, 256, 0, stream>>>(counts, block_offs, row_start, cursor, n_nodes);
    k_scatter<<<(n_edges + 255) / 256, 256, 0, stream>>>(src, dst, cursor, sorted_src, n_edges);

    // Layer 1
    k_gemm1<<<(n_nodes + 63) / 64, 256, 0, stream>>>(x, W1, a1s, a1d, h1b, es1, ed1, n_nodes);
    k_gather1<<<(n_nodes + 3) / 4, 256, 0, stream>>>(row_start, sorted_src, h1b, es1, ed1, h1, n_nodes);

    // Layer 2
    k_gemm2<<<(n_nodes + 15) / 16, 256, 0, stream>>>(h1, W2, a2s, a2d, h2b, es2, ed2, n_nodes);
    k_gather2<<<(n_nodes + 15) / 16, 256, 0, stream>>>(row_start, sorted_src, h2b, es2, ed2, out, n_nodes);
}

// Round 5
// 610.158 us; speedup vs baseline: 8.2571x; 1.0913x over previous
//
#include <hip/hip_runtime.h>
#include <hip/hip_bf16.h>

#define F_IN 512
#define H1 8
#define D1 8
#define F_MID 64   // H1*D1
#define C 16
#define NEG_SLOPE 0.2f
#define SCAN_CHUNK 1024

typedef __attribute__((ext_vector_type(8))) short bf16x8;
typedef __attribute__((ext_vector_type(4))) float f32x4;

static __device__ __forceinline__ unsigned short f2bf(float f) {
    __hip_bfloat16 h = __float2bfloat16(f);
    return *(unsigned short*)&h;
}

// ============ counting-sort CSR build (by dst) ============
__global__ void k_hist(const int* __restrict__ dst, int* __restrict__ counts, int n_edges) {
    int e = blockIdx.x * blockDim.x + threadIdx.x;
    if (e < n_edges) atomicAdd(&counts[dst[e]], 1);
}

__global__ __launch_bounds__(256) void k_scan_reduce(const int* __restrict__ counts,
                                                     int* __restrict__ block_sums, int n) {
    const int t = threadIdx.x;
    const int base = blockIdx.x * SCAN_CHUNK + t * 4;
    int s = 0;
#pragma unroll
    for (int j = 0; j < 4; ++j) {
        int idx = base + j;
        if (idx < n) s += counts[idx];
    }
#pragma unroll
    for (int off = 1; off < 64; off <<= 1) s += __shfl_xor(s, off, 64);
    __shared__ int ws[4];
    if ((t & 63) == 0) ws[t >> 6] = s;
    __syncthreads();
    if (t == 0) block_sums[blockIdx.x] = ws[0] + ws[1] + ws[2] + ws[3];
}

__global__ __launch_bounds__(256) void k_scan_sums(int* __restrict__ block_sums,
                                                   int* __restrict__ block_offs,
                                                   int* __restrict__ row_start_last,
                                                   int nb) {
    __shared__ int sh[256];
    const int t = threadIdx.x;
    sh[t] = (t < nb) ? block_sums[t] : 0;
    __syncthreads();
#pragma unroll
    for (int d = 1; d < 256; d <<= 1) {
        int v = (t >= d) ? sh[t - d] : 0;
        __syncthreads();
        sh[t] += v;
        __syncthreads();
    }
    if (t < nb) block_offs[t] = sh[t] - block_sums[t];
    if (t == 255) *row_start_last = sh[255];
}

__global__ __launch_bounds__(256) void k_scan_apply(const int* __restrict__ counts,
                                                    const int* __restrict__ block_offs,
                                                    int* __restrict__ row_start,
                                                    int* __restrict__ cursor, int n) {
    const int t = threadIdx.x;
    const int base = blockIdx.x * SCAN_CHUNK + t * 4;
    int c[4];
#pragma unroll
    for (int j = 0; j < 4; ++j) c[j] = (base + j < n) ? counts[base + j] : 0;
    const int tsum = c[0] + c[1] + c[2] + c[3];
    int isc = tsum;
#pragma unroll
    for (int off = 1; off < 64; off <<= 1) {
        int v = __shfl_up(isc, off, 64);
        if ((t & 63) >= off) isc += v;
    }
    __shared__ int wsum[4];
    if ((t & 63) == 63) wsum[t >> 6] = isc;
    __syncthreads();
    int woff = 0;
    const int w = t >> 6;
    for (int i = 0; i < 4; ++i) if (i < w) woff += wsum[i];
    int off = block_offs[blockIdx.x] + woff + (isc - tsum);
#pragma unroll
    for (int j = 0; j < 4; ++j) {
        int idx = base + j;
        if (idx < n) { row_start[idx] = off; cursor[idx] = off; }
        off += c[j];
    }
}

__global__ void k_scatter(const int* __restrict__ src, const int* __restrict__ dst,
                          int* __restrict__ cursor, int* __restrict__ sorted_src, int n_edges) {
    int e = blockIdx.x * blockDim.x + threadIdx.x;
    if (e >= n_edges) return;
    int pos = atomicAdd(&cursor[dst[e]], 1);
    sorted_src[pos] = src[e];
}

// ============ W1 transpose + bf16 convert: W1[512,64] -> W1T[64,512] ============
__global__ __launch_bounds__(256) void k_w1t(const float* __restrict__ W1,
                                             __hip_bfloat16* __restrict__ w1t) {
    int idx = blockIdx.x * 256 + threadIdx.x;   // 0 .. 32767
    int k = idx >> 6, n = idx & 63;
    w1t[n * F_IN + k] = __float2bfloat16(W1[idx]);
}

// ============ Layer 1 MFMA GEMM: x[N,512] @ W1[512,64] -> h1b (bf16) + es1/ed1 (fp32)
// A-operand = W1T rows (m = W-col), B-operand = x rows (n = node).
// D[m=wcol][n=node]; C layout: col=lane&15 (node), row=quad*4+reg (wcol).
__global__ __launch_bounds__(256) void k_gemm1(const float* __restrict__ x,
                                               const __hip_bfloat16* __restrict__ w1t,
                                               const float* __restrict__ a1s,
                                               const float* __restrict__ a1d,
                                               __hip_bfloat16* __restrict__ h1b,
                                               float* __restrict__ es1,
                                               float* __restrict__ ed1, int n_nodes) {
    __shared__ unsigned short Xs[64][72];   // node-rows x k (bf16 bits), row=144B
    __shared__ unsigned short Ws[64][72];   // wcol-rows x k
    __shared__ float sas[64], sad[64];
    const int t = threadIdx.x;
    if (t < 64) sas[t] = a1s[t];
    else if (t < 128) sad[t - 64] = a1d[t - 64];

    const int wv = t >> 6, l = t & 63;
    const int q = l >> 4, m16 = l & 15;
    const int rowbase = blockIdx.x * 64;

    const int sr = t >> 2, sf = t & 3;      // staging: row 0..63, quarter 0..3
    int gx = rowbase + sr;
    gx = gx < n_nodes ? gx : n_nodes - 1;
    const float* xrow = x + (size_t)gx * F_IN;
    const __hip_bfloat16* wrow = w1t + (size_t)sr * F_IN;

    f32x4 acc[4];
#pragma unroll
    for (int i = 0; i < 4; ++i) acc[i] = (f32x4){0.f, 0.f, 0.f, 0.f};

    for (int kt = 0; kt < F_IN; kt += 64) {
        // stage X: 64 rows x 64 k fp32 -> bf16 (4 float4 per thread)
#pragma unroll
        for (int j = 0; j < 4; ++j) {
            float4 v = *(const float4*)(xrow + kt + sf * 16 + j * 4);
            ushort4 b;
            b.x = f2bf(v.x); b.y = f2bf(v.y); b.z = f2bf(v.z); b.w = f2bf(v.w);
            *(ushort4*)&Xs[sr][sf * 16 + j * 4] = b;
        }
        // stage W1T: 64 rows x 64 k bf16 (2 x 16B per thread)
#pragma unroll
        for (int j = 0; j < 2; ++j) {
            *(int4*)&Ws[sr][sf * 16 + j * 8] =
                *(const int4*)(wrow + kt + sf * 16 + j * 8);
        }
        __syncthreads();
#pragma unroll
        for (int kk = 0; kk < 2; ++kk) {
            bf16x8 bfrag = *(const bf16x8*)&Xs[wv * 16 + m16][kk * 32 + q * 8];
#pragma unroll
            for (int tn = 0; tn < 4; ++tn) {
                bf16x8 afrag = *(const bf16x8*)&Ws[tn * 16 + m16][kk * 32 + q * 8];
                acc[tn] = __builtin_amdgcn_mfma_f32_16x16x32_bf16(afrag, bfrag, acc[tn], 0, 0, 0);
            }
        }
        __syncthreads();
    }

    // epilogue: lane holds node = rowbase + wv*16 + m16; per tile tn: wcols tn*16+q*4 .. +3
    const int node = rowbase + wv * 16 + m16;
    const bool ok = node < n_nodes;
#pragma unroll
    for (int tn = 0; tn < 4; ++tn) {
        const f32x4 a = acc[tn];
        const int nw0 = tn * 16 + q * 4;
        float vs = a.x * sas[nw0] + a.y * sas[nw0 + 1] + a.z * sas[nw0 + 2] + a.w * sas[nw0 + 3];
        float vd = a.x * sad[nw0] + a.y * sad[nw0 + 1] + a.z * sad[nw0 + 2] + a.w * sad[nw0 + 3];
        vs += __shfl_xor(vs, 16, 64);   // combine quad pairs (0,1) and (2,3): full head
        vd += __shfl_xor(vd, 16, 64);
        if (ok) {
            ushort4 b;
            b.x = f2bf(a.x); b.y = f2bf(a.y); b.z = f2bf(a.z); b.w = f2bf(a.w);
            *(ushort4*)(h1b + (size_t)node * F_MID + nw0) = b;
            if ((q & 1) == 0) {
                const int head = 2 * tn + (q >> 1);
                es1[node * H1 + head] = vs;
                ed1[node * H1 + head] = vd;
            }
        }
    }
}

// ============ Layer 1 gather: wave per node, lane = feature, 4-wide edge unroll ============
__global__ __launch_bounds__(256) void k_gather1(const int* __restrict__ row_start,
                                                 const int* __restrict__ sorted_src,
                                                 const __hip_bfloat16* __restrict__ h1b,
                                                 const float* __restrict__ es1,
                                                 const float* __restrict__ ed1,
                                                 float* __restrict__ h1, int n_nodes) {
    const int n = blockIdx.x * 4 + (threadIdx.x >> 6);
    if (n >= n_nodes) return;
    const int lane = threadIdx.x & 63;
    const int h = lane >> 3;
    const float edh = ed1[n * H1 + h];
    const int beg = row_start[n], end = row_start[n + 1];
    float acc = 0.f, den = 0.f;
    for (int base = beg; base < end; base += 64) {
        const int m = min(64, end - base);
        const int li = lane < m ? lane : (m - 1);
        const int myS = sorted_src[base + li];
        int j = 0;
        for (; j + 4 <= m; j += 4) {
            const int s0 = __shfl(myS, j, 64), s1 = __shfl(myS, j + 1, 64);
            const int s2 = __shfl(myS, j + 2, 64), s3 = __shfl(myS, j + 3, 64);
            float e0 = es1[s0 * H1 + h], e1 = es1[s1 * H1 + h];
            float e2 = es1[s2 * H1 + h], e3 = es1[s3 * H1 + h];
            const float f0 = __bfloat162float(h1b[(size_t)s0 * F_MID + lane]);
            const float f1 = __bfloat162float(h1b[(size_t)s1 * F_MID + lane]);
            const float f2 = __bfloat162float(h1b[(size_t)s2 * F_MID + lane]);
            const float f3 = __bfloat162float(h1b[(size_t)s3 * F_MID + lane]);
            e0 += edh; e1 += edh; e2 += edh; e3 += edh;
            e0 = e0 > 0.f ? e0 : NEG_SLOPE * e0;
            e1 = e1 > 0.f ? e1 : NEG_SLOPE * e1;
            e2 = e2 > 0.f ? e2 : NEG_SLOPE * e2;
            e3 = e3 > 0.f ? e3 : NEG_SLOPE * e3;
            const float w0 = __expf(e0), w1 = __expf(e1), w2 = __expf(e2), w3 = __expf(e3);
            acc += w0 * f0 + w1 * f1 + w2 * f2 + w3 * f3;
            den += (w0 + w1) + (w2 + w3);
        }
        for (; j < m; ++j) {
            const int s = __shfl(myS, j, 64);
            float ev = es1[s * H1 + h] + edh;
            ev = ev > 0.f ? ev : NEG_SLOPE * ev;
            const float w = __expf(ev);
            acc += w * __bfloat162float(h1b[(size_t)s * F_MID + lane]);
            den += w;
        }
    }
    // self-loop
    float evs = es1[n * H1 + h] + edh;
    evs = evs > 0.f ? evs : NEG_SLOPE * evs;
    const float ws = __expf(evs);
    acc += ws * __bfloat162float(h1b[(size_t)n * F_MID + lane]);
    den += ws;
    float v = acc / den;
    v = v > 0.f ? v : expm1f(v);   // ELU
    h1[(size_t)n * F_MID + lane] = v;
}

// ============ Layer 2 transform: h1[N,64] @ W2[64,16] -> h2b (bf16) + es2/ed2 ============
__global__ void k_gemm2(const float* __restrict__ h1, const float* __restrict__ W2,
                        const float* __restrict__ a2s, const float* __restrict__ a2d,
                        __hip_bfloat16* __restrict__ h2b, float* __restrict__ es2,
                        float* __restrict__ ed2, int n_nodes) {
    __shared__ float w2s[F_MID * C];
    __shared__ float h1s[16][F_MID + 1];
    const int t = threadIdx.x;
    const int nb = blockIdx.x * 16;
    for (int i = t; i < F_MID * C; i += 256) w2s[i] = W2[i];
    for (int i = t; i < 16 * F_MID; i += 256) {
        int r = i >> 6, k = i & 63;
        int n = nb + r;
        h1s[r][k] = h1[(size_t)(n < n_nodes ? n : n_nodes - 1) * F_MID + k];
    }
    __syncthreads();
    const int r = t >> 4, c = t & 15;
    const int n = nb + r;
    float acc = 0.f;
#pragma unroll
    for (int k = 0; k < F_MID; ++k) acc += h1s[r][k] * w2s[k * C + c];
    float vs = acc * a2s[c], vd = acc * a2d[c];
#pragma unroll
    for (int off = 1; off < 16; off <<= 1) {
        vs += __shfl_xor(vs, off, 64);
        vd += __shfl_xor(vd, off, 64);
    }
    if (n < n_nodes) {
        h2b[(size_t)n * C + c] = __float2bfloat16(acc);
        if (c == 0) { es2[n] = vs; ed2[n] = vd; }
    }
}

// ============ Layer 2 gather + log_softmax: 16 lanes per node, 4-wide unroll ============
__global__ __launch_bounds__(256) void k_gather2(const int* __restrict__ row_start,
                                                 const int* __restrict__ sorted_src,
                                                 const __hip_bfloat16* __restrict__ h2b,
                                                 const float* __restrict__ es2,
                                                 const float* __restrict__ ed2,
                                                 float* __restrict__ out, int n_nodes) {
    const int n = blockIdx.x * 16 + (threadIdx.x >> 4);
    if (n >= n_nodes) return;
    const int lane = threadIdx.x & 63;
    const int c = lane & 15;
    const int g = lane >> 4;
    const float ed = ed2[n];
    const int beg = row_start[n], end = row_start[n + 1];
    float acc = 0.f, den = 0.f;
    for (int base = beg; base < end; base += 16) {
        const int m = min(16, end - base);
        const int li = c < m ? c : (m - 1);
        const int myS = sorted_src[base + li];
        int j = 0;
        for (; j + 4 <= m; j += 4) {
            const int s0 = __shfl(myS, g * 16 + j, 64), s1 = __shfl(myS, g * 16 + j + 1, 64);
            const int s2 = __shfl(myS, g * 16 + j + 2, 64), s3 = __shfl(myS, g * 16 + j + 3, 64);
            float e0 = es2[s0] + ed, e1 = es2[s1] + ed, e2 = es2[s2] + ed, e3 = es2[s3] + ed;
            const float f0 = __bfloat162float(h2b[(size_t)s0 * C + c]);
            const float f1 = __bfloat162float(h2b[(size_t)s1 * C + c]);
            const float f2 = __bfloat162float(h2b[(size_t)s2 * C + c]);
            const float f3 = __bfloat162float(h2b[(size_t)s3 * C + c]);
            e0 = e0 > 0.f ? e0 : NEG_SLOPE * e0;
            e1 = e1 > 0.f ? e1 : NEG_SLOPE * e1;
            e2 = e2 > 0.f ? e2 : NEG_SLOPE * e2;
            e3 = e3 > 0.f ? e3 : NEG_SLOPE * e3;
            const float w0 = __expf(e0), w1 = __expf(e1), w2 = __expf(e2), w3 = __expf(e3);
            acc += w0 * f0 + w1 * f1 + w2 * f2 + w3 * f3;
            den += (w0 + w1) + (w2 + w3);
        }
        for (; j < m; ++j) {
            const int s = __shfl(myS, g * 16 + j, 64);
            float ev = es2[s] + ed;
            ev = ev > 0.f ? ev : NEG_SLOPE * ev;
            const float w = __expf(ev);
            acc += w * __bfloat162float(h2b[(size_t)s * C + c]);
            den += w;
        }
    }
    float evs = es2[n] + ed;
    evs = evs > 0.f ? evs : NEG_SLOPE * evs;
    const float ws = __expf(evs);
    acc += ws * __bfloat162float(h2b[(size_t)n * C + c]);
    den += ws;
    const float v = acc / den;
    float mx = v;
#pragma unroll
    for (int off = 1; off < 16; off <<= 1) mx = fmaxf(mx, __shfl_xor(mx, off, 64));
    float se = __expf(v - mx);
#pragma unroll
    for (int off = 1; off < 16; off <<= 1) se += __shfl_xor(se, off, 64);
    out[(size_t)n * C + c] = v - mx - __logf(se);
}

extern "C" void kernel_launch(void* const* d_in, const int* in_sizes, int n_in,
                              void* d_out, int out_size, void* d_ws, size_t ws_size,
                              hipStream_t stream) {
    const float* x   = (const float*)d_in[0];
    const int*   ei  = (const int*)d_in[1];
    const float* W1  = (const float*)d_in[2];
    const float* a1s = (const float*)d_in[3];
    const float* a1d = (const float*)d_in[4];
    const float* W2  = (const float*)d_in[5];
    const float* a2s = (const float*)d_in[6];
    const float* a2d = (const float*)d_in[7];
    float* out = (float*)d_out;

    const int n_nodes = in_sizes[0] / F_IN;   // 100000
    const int n_edges = in_sizes[1] / 2;      // 1600000
    const int* src = ei;
    const int* dst = ei + n_edges;
    const int n_scan_blocks = (n_nodes + SCAN_CHUNK - 1) / SCAN_CHUNK;

    // workspace layout
    float* fws = (float*)d_ws;
    float* es1 = fws;                              // N*8
    float* ed1 = es1 + (size_t)n_nodes * H1;       // N*8
    float* h1  = ed1 + (size_t)n_nodes * H1;       // N*64
    float* es2 = h1  + (size_t)n_nodes * F_MID;    // N
    float* ed2 = es2 + n_nodes;                    // N
    __hip_bfloat16* h1b = (__hip_bfloat16*)(ed2 + n_nodes);   // N*64 bf16
    __hip_bfloat16* h2b = h1b + (size_t)n_nodes * F_MID;      // N*16 bf16
    __hip_bfloat16* w1t = h2b + (size_t)n_nodes * C;          // 64*512 bf16
    int* iws        = (int*)(w1t + F_IN * F_MID);
    int* counts     = iws;                         // N (zeroed)
    int* row_start  = counts + n_nodes;            // N+1
    int* cursor     = row_start + n_nodes + 1;     // N
    int* sorted_src = cursor + n_nodes;            // E
    int* block_sums = sorted_src + n_edges;        // 256
    int* block_offs = block_sums + 256;            // 256

    hipMemsetAsync(counts, 0, (size_t)n_nodes * sizeof(int), stream);

    // CSR build (shared by both layers)
    k_hist<<<(n_edges + 255) / 256, 256, 0, stream>>>(dst, counts, n_edges);
    k_scan_reduce<<<n_scan_blocks, 256, 0, stream>>>(counts, block_sums, n_nodes);
    k_scan_sums<<<1, 256, 0, stream>>>(block_sums, block_offs, &row_start[n_nodes], n_scan_blocks);
    k_scan_apply<<<n_scan_blocks, 256, 0, stream>>>(counts, block_offs, row_start, cursor, n_nodes);
    k_scatter<<<(n_edges + 255) / 256, 256, 0, stream>>>(src, dst, cursor, sorted_src, n_edges);

    // Layer 1
    k_w1t<<<(F_IN * F_MID) / 256, 256, 0, stream>>>(W1, w1t);
    k_gemm1<<<(n_nodes + 63) / 64, 256, 0, stream>>>(x, w1t, a1s, a1d, h1b, es1, ed1, n_nodes);
    k_gather1<<<(n_nodes + 3) / 4, 256, 0, stream>>>(row_start, sorted_src, h1b, es1, ed1, h1, n_nodes);

    // Layer 2
    k_gemm2<<<(n_nodes + 15) / 16, 256, 0, stream>>>(h1, W2, a2s, a2d, h2b, es2, ed2, n_nodes);
    k_gather2<<<(n_nodes + 15) / 16, 256, 0, stream>>>(row_start, sorted_src, h2b, es2, ed2, out, n_nodes);
}

// Round 6
// 535.832 us; speedup vs baseline: 9.4024x; 1.1387x over previous
//
#include <hip/hip_runtime.h>
#include <hip/hip_bf16.h>

#define F_IN 512
#define H1 8
#define D1 8
#define F_MID 64   // H1*D1
#define C 16
#define NEG_SLOPE 0.2f
#define SCAN_CHUNK 1024
#define BIN_CHUNK 8192
#define NB_MAX 1024
#define BUCKET_SHIFT 7        // 128 nodes per bucket
#define BUCKET_STRIDE 3072    // capacity per bucket (mean 2048, +22 sigma)

typedef __attribute__((ext_vector_type(8))) short bf16x8;
typedef __attribute__((ext_vector_type(4))) float f32x4;

static __device__ __forceinline__ unsigned short f2bf(float f) {
    __hip_bfloat16 h = __float2bfloat16(f);
    return *(unsigned short*)&h;
}

// ============ bucket sort pass 1: bin edges by dst>>7 with LDS aggregation ============
__global__ __launch_bounds__(256) void k_bin(const int* __restrict__ src,
                                             const int* __restrict__ dst,
                                             int* __restrict__ gcur,
                                             int2* __restrict__ bucketed,
                                             int n_edges, int nb) {
    __shared__ int cnt[NB_MAX];
    __shared__ int base[NB_MAX];
    const int t = threadIdx.x;
    const int eb = blockIdx.x * BIN_CHUNK;
    for (int b = t; b < nb; b += 256) cnt[b] = 0;
    __syncthreads();
#pragma unroll
    for (int i = 0; i < BIN_CHUNK / 256; ++i) {
        int e = eb + i * 256 + t;
        if (e < n_edges) atomicAdd(&cnt[dst[e] >> BUCKET_SHIFT], 1);
    }
    __syncthreads();
    for (int b = t; b < nb; b += 256) {
        int c = cnt[b];
        base[b] = c > 0 ? atomicAdd(&gcur[b], c) : 0;
        cnt[b] = 0;
    }
    __syncthreads();
#pragma unroll
    for (int i = 0; i < BIN_CHUNK / 256; ++i) {
        int e = eb + i * 256 + t;
        if (e < n_edges) {
            int d = dst[e];
            int b = d >> BUCKET_SHIFT;
            int local = atomicAdd(&cnt[b], 1);
            bucketed[(size_t)b * BUCKET_STRIDE + base[b] + local] = make_int2(src[e], d);
        }
    }
}

// ============ bucket sort pass 2a: per-bucket LDS histogram -> counts ============
__global__ __launch_bounds__(256) void k_bhist(const int* __restrict__ gcur,
                                               const int2* __restrict__ bucketed,
                                               int* __restrict__ counts, int n_nodes) {
    __shared__ int cnt[1 << BUCKET_SHIFT];
    const int t = threadIdx.x;
    const int b = blockIdx.x;
    if (t < (1 << BUCKET_SHIFT)) cnt[t] = 0;
    __syncthreads();
    const int total = gcur[b];
    const int2* bp = bucketed + (size_t)b * BUCKET_STRIDE;
    for (int i = t; i < total; i += 256)
        atomicAdd(&cnt[bp[i].y & ((1 << BUCKET_SHIFT) - 1)], 1);
    __syncthreads();
    if (t < (1 << BUCKET_SHIFT)) {
        int node = (b << BUCKET_SHIFT) + t;
        if (node < n_nodes) counts[node] = cnt[t];
    }
}

// ============ bucket sort pass 2b: per-bucket placement (L2-local) ============
__global__ __launch_bounds__(256) void k_bsort(const int* __restrict__ gcur,
                                               const int2* __restrict__ bucketed,
                                               int* __restrict__ cursor,
                                               int* __restrict__ sorted_src) {
    const int b = blockIdx.x;
    const int total = gcur[b];
    const int2* bp = bucketed + (size_t)b * BUCKET_STRIDE;
    for (int i = threadIdx.x; i < total; i += 256) {
        int2 ed = bp[i];
        int pos = atomicAdd(&cursor[ed.y], 1);
        sorted_src[pos] = ed.x;
    }
}

// ============ device-wide scan over counts ============
__global__ __launch_bounds__(256) void k_scan_reduce(const int* __restrict__ counts,
                                                     int* __restrict__ block_sums, int n) {
    const int t = threadIdx.x;
    const int base = blockIdx.x * SCAN_CHUNK + t * 4;
    int s = 0;
#pragma unroll
    for (int j = 0; j < 4; ++j) {
        int idx = base + j;
        if (idx < n) s += counts[idx];
    }
#pragma unroll
    for (int off = 1; off < 64; off <<= 1) s += __shfl_xor(s, off, 64);
    __shared__ int ws[4];
    if ((t & 63) == 0) ws[t >> 6] = s;
    __syncthreads();
    if (t == 0) block_sums[blockIdx.x] = ws[0] + ws[1] + ws[2] + ws[3];
}

__global__ __launch_bounds__(256) void k_scan_sums(int* __restrict__ block_sums,
                                                   int* __restrict__ block_offs,
                                                   int* __restrict__ row_start_last,
                                                   int nb) {
    __shared__ int sh[256];
    const int t = threadIdx.x;
    sh[t] = (t < nb) ? block_sums[t] : 0;
    __syncthreads();
#pragma unroll
    for (int d = 1; d < 256; d <<= 1) {
        int v = (t >= d) ? sh[t - d] : 0;
        __syncthreads();
        sh[t] += v;
        __syncthreads();
    }
    if (t < nb) block_offs[t] = sh[t] - block_sums[t];
    if (t == 255) *row_start_last = sh[255];
}

__global__ __launch_bounds__(256) void k_scan_apply(const int* __restrict__ counts,
                                                    const int* __restrict__ block_offs,
                                                    int* __restrict__ row_start,
                                                    int* __restrict__ cursor, int n) {
    const int t = threadIdx.x;
    const int base = blockIdx.x * SCAN_CHUNK + t * 4;
    int c[4];
#pragma unroll
    for (int j = 0; j < 4; ++j) c[j] = (base + j < n) ? counts[base + j] : 0;
    const int tsum = c[0] + c[1] + c[2] + c[3];
    int isc = tsum;
#pragma unroll
    for (int off = 1; off < 64; off <<= 1) {
        int v = __shfl_up(isc, off, 64);
        if ((t & 63) >= off) isc += v;
    }
    __shared__ int wsum[4];
    if ((t & 63) == 63) wsum[t >> 6] = isc;
    __syncthreads();
    int woff = 0;
    const int w = t >> 6;
    for (int i = 0; i < 4; ++i) if (i < w) woff += wsum[i];
    int off = block_offs[blockIdx.x] + woff + (isc - tsum);
#pragma unroll
    for (int j = 0; j < 4; ++j) {
        int idx = base + j;
        if (idx < n) { row_start[idx] = off; cursor[idx] = off; }
        off += c[j];
    }
}

// ============ W1 transpose + bf16 convert: W1[512,64] -> W1T[64,512] ============
__global__ __launch_bounds__(256) void k_w1t(const float* __restrict__ W1,
                                             __hip_bfloat16* __restrict__ w1t) {
    int idx = blockIdx.x * 256 + threadIdx.x;
    int k = idx >> 6, n = idx & 63;
    w1t[n * F_IN + k] = __float2bfloat16(W1[idx]);
}

// ============ Layer 1 MFMA GEMM: x[N,512] @ W1[512,64] -> h1b (bf16) + es1/ed1 ============
__global__ __launch_bounds__(256) void k_gemm1(const float* __restrict__ x,
                                               const __hip_bfloat16* __restrict__ w1t,
                                               const float* __restrict__ a1s,
                                               const float* __restrict__ a1d,
                                               __hip_bfloat16* __restrict__ h1b,
                                               float* __restrict__ es1,
                                               float* __restrict__ ed1, int n_nodes) {
    __shared__ unsigned short Xs[64][72];
    __shared__ unsigned short Ws[64][72];
    __shared__ float sas[64], sad[64];
    const int t = threadIdx.x;
    if (t < 64) sas[t] = a1s[t];
    else if (t < 128) sad[t - 64] = a1d[t - 64];

    const int wv = t >> 6, l = t & 63;
    const int q = l >> 4, m16 = l & 15;
    const int rowbase = blockIdx.x * 64;

    const int sr = t >> 2, sf = t & 3;
    int gx = rowbase + sr;
    gx = gx < n_nodes ? gx : n_nodes - 1;
    const float* xrow = x + (size_t)gx * F_IN;
    const __hip_bfloat16* wrow = w1t + (size_t)sr * F_IN;

    f32x4 acc[4];
#pragma unroll
    for (int i = 0; i < 4; ++i) acc[i] = (f32x4){0.f, 0.f, 0.f, 0.f};

    for (int kt = 0; kt < F_IN; kt += 64) {
#pragma unroll
        for (int j = 0; j < 4; ++j) {
            float4 v = *(const float4*)(xrow + kt + sf * 16 + j * 4);
            ushort4 b;
            b.x = f2bf(v.x); b.y = f2bf(v.y); b.z = f2bf(v.z); b.w = f2bf(v.w);
            *(ushort4*)&Xs[sr][sf * 16 + j * 4] = b;
        }
#pragma unroll
        for (int j = 0; j < 2; ++j) {
            *(int4*)&Ws[sr][sf * 16 + j * 8] =
                *(const int4*)(wrow + kt + sf * 16 + j * 8);
        }
        __syncthreads();
#pragma unroll
        for (int kk = 0; kk < 2; ++kk) {
            bf16x8 bfrag = *(const bf16x8*)&Xs[wv * 16 + m16][kk * 32 + q * 8];
#pragma unroll
            for (int tn = 0; tn < 4; ++tn) {
                bf16x8 afrag = *(const bf16x8*)&Ws[tn * 16 + m16][kk * 32 + q * 8];
                acc[tn] = __builtin_amdgcn_mfma_f32_16x16x32_bf16(afrag, bfrag, acc[tn], 0, 0, 0);
            }
        }
        __syncthreads();
    }

    const int node = rowbase + wv * 16 + m16;
    const bool ok = node < n_nodes;
#pragma unroll
    for (int tn = 0; tn < 4; ++tn) {
        const f32x4 a = acc[tn];
        const int nw0 = tn * 16 + q * 4;
        float vs = a.x * sas[nw0] + a.y * sas[nw0 + 1] + a.z * sas[nw0 + 2] + a.w * sas[nw0 + 3];
        float vd = a.x * sad[nw0] + a.y * sad[nw0 + 1] + a.z * sad[nw0 + 2] + a.w * sad[nw0 + 3];
        vs += __shfl_xor(vs, 16, 64);
        vd += __shfl_xor(vd, 16, 64);
        if (ok) {
            ushort4 b;
            b.x = f2bf(a.x); b.y = f2bf(a.y); b.z = f2bf(a.z); b.w = f2bf(a.w);
            *(ushort4*)(h1b + (size_t)node * F_MID + nw0) = b;
            if ((q & 1) == 0) {
                const int head = 2 * tn + (q >> 1);
                es1[node * H1 + head] = vs;
                ed1[node * H1 + head] = vd;
            }
        }
    }
}

// ============ Layer 1 gather: wave per node, lane = feature, 4-wide edge unroll ============
__global__ __launch_bounds__(256) void k_gather1(const int* __restrict__ row_start,
                                                 const int* __restrict__ sorted_src,
                                                 const __hip_bfloat16* __restrict__ h1b,
                                                 const float* __restrict__ es1,
                                                 const float* __restrict__ ed1,
                                                 float* __restrict__ h1, int n_nodes) {
    const int n = blockIdx.x * 4 + (threadIdx.x >> 6);
    if (n >= n_nodes) return;
    const int lane = threadIdx.x & 63;
    const int h = lane >> 3;
    const float edh = ed1[n * H1 + h];
    const int beg = row_start[n], end = row_start[n + 1];
    float acc = 0.f, den = 0.f;
    for (int base = beg; base < end; base += 64) {
        const int m = min(64, end - base);
        const int li = lane < m ? lane : (m - 1);
        const int myS = sorted_src[base + li];
        int j = 0;
        for (; j + 4 <= m; j += 4) {
            const int s0 = __shfl(myS, j, 64), s1 = __shfl(myS, j + 1, 64);
            const int s2 = __shfl(myS, j + 2, 64), s3 = __shfl(myS, j + 3, 64);
            float e0 = es1[s0 * H1 + h], e1 = es1[s1 * H1 + h];
            float e2 = es1[s2 * H1 + h], e3 = es1[s3 * H1 + h];
            const float f0 = __bfloat162float(h1b[(size_t)s0 * F_MID + lane]);
            const float f1 = __bfloat162float(h1b[(size_t)s1 * F_MID + lane]);
            const float f2 = __bfloat162float(h1b[(size_t)s2 * F_MID + lane]);
            const float f3 = __bfloat162float(h1b[(size_t)s3 * F_MID + lane]);
            e0 += edh; e1 += edh; e2 += edh; e3 += edh;
            e0 = e0 > 0.f ? e0 : NEG_SLOPE * e0;
            e1 = e1 > 0.f ? e1 : NEG_SLOPE * e1;
            e2 = e2 > 0.f ? e2 : NEG_SLOPE * e2;
            e3 = e3 > 0.f ? e3 : NEG_SLOPE * e3;
            const float w0 = __expf(e0), w1 = __expf(e1), w2 = __expf(e2), w3 = __expf(e3);
            acc += w0 * f0 + w1 * f1 + w2 * f2 + w3 * f3;
            den += (w0 + w1) + (w2 + w3);
        }
        for (; j < m; ++j) {
            const int s = __shfl(myS, j, 64);
            float ev = es1[s * H1 + h] + edh;
            ev = ev > 0.f ? ev : NEG_SLOPE * ev;
            const float w = __expf(ev);
            acc += w * __bfloat162float(h1b[(size_t)s * F_MID + lane]);
            den += w;
        }
    }
    float evs = es1[n * H1 + h] + edh;
    evs = evs > 0.f ? evs : NEG_SLOPE * evs;
    const float ws = __expf(evs);
    acc += ws * __bfloat162float(h1b[(size_t)n * F_MID + lane]);
    den += ws;
    float v = acc / den;
    v = v > 0.f ? v : expm1f(v);   // ELU
    h1[(size_t)n * F_MID + lane] = v;
}

// ============ Layer 2 transform: h1[N,64] @ W2[64,16] -> h2b (bf16) + es2/ed2 ============
__global__ void k_gemm2(const float* __restrict__ h1, const float* __restrict__ W2,
                        const float* __restrict__ a2s, const float* __restrict__ a2d,
                        __hip_bfloat16* __restrict__ h2b, float* __restrict__ es2,
                        float* __restrict__ ed2, int n_nodes) {
    __shared__ float w2s[F_MID * C];
    __shared__ float h1s[16][F_MID + 1];
    const int t = threadIdx.x;
    const int nb = blockIdx.x * 16;
    for (int i = t; i < F_MID * C; i += 256) w2s[i] = W2[i];
    for (int i = t; i < 16 * F_MID; i += 256) {
        int r = i >> 6, k = i & 63;
        int n = nb + r;
        h1s[r][k] = h1[(size_t)(n < n_nodes ? n : n_nodes - 1) * F_MID + k];
    }
    __syncthreads();
    const int r = t >> 4, c = t & 15;
    const int n = nb + r;
    float acc = 0.f;
#pragma unroll
    for (int k = 0; k < F_MID; ++k) acc += h1s[r][k] * w2s[k * C + c];
    float vs = acc * a2s[c], vd = acc * a2d[c];
#pragma unroll
    for (int off = 1; off < 16; off <<= 1) {
        vs += __shfl_xor(vs, off, 64);
        vd += __shfl_xor(vd, off, 64);
    }
    if (n < n_nodes) {
        h2b[(size_t)n * C + c] = __float2bfloat16(acc);
        if (c == 0) { es2[n] = vs; ed2[n] = vd; }
    }
}

// ============ Layer 2 gather + log_softmax: 16 lanes per node, 4-wide unroll ============
__global__ __launch_bounds__(256) void k_gather2(const int* __restrict__ row_start,
                                                 const int* __restrict__ sorted_src,
                                                 const __hip_bfloat16* __restrict__ h2b,
                                                 const float* __restrict__ es2,
                                                 const float* __restrict__ ed2,
                                                 float* __restrict__ out, int n_nodes) {
    const int n = blockIdx.x * 16 + (threadIdx.x >> 4);
    if (n >= n_nodes) return;
    const int lane = threadIdx.x & 63;
    const int c = lane & 15;
    const int g = lane >> 4;
    const float ed = ed2[n];
    const int beg = row_start[n], end = row_start[n + 1];
    float acc = 0.f, den = 0.f;
    for (int base = beg; base < end; base += 16) {
        const int m = min(16, end - base);
        const int li = c < m ? c : (m - 1);
        const int myS = sorted_src[base + li];
        int j = 0;
        for (; j + 4 <= m; j += 4) {
            const int s0 = __shfl(myS, g * 16 + j, 64), s1 = __shfl(myS, g * 16 + j + 1, 64);
            const int s2 = __shfl(myS, g * 16 + j + 2, 64), s3 = __shfl(myS, g * 16 + j + 3, 64);
            float e0 = es2[s0] + ed, e1 = es2[s1] + ed, e2 = es2[s2] + ed, e3 = es2[s3] + ed;
            const float f0 = __bfloat162float(h2b[(size_t)s0 * C + c]);
            const float f1 = __bfloat162float(h2b[(size_t)s1 * C + c]);
            const float f2 = __bfloat162float(h2b[(size_t)s2 * C + c]);
            const float f3 = __bfloat162float(h2b[(size_t)s3 * C + c]);
            e0 = e0 > 0.f ? e0 : NEG_SLOPE * e0;
            e1 = e1 > 0.f ? e1 : NEG_SLOPE * e1;
            e2 = e2 > 0.f ? e2 : NEG_SLOPE * e2;
            e3 = e3 > 0.f ? e3 : NEG_SLOPE * e3;
            const float w0 = __expf(e0), w1 = __expf(e1), w2 = __expf(e2), w3 = __expf(e3);
            acc += w0 * f0 + w1 * f1 + w2 * f2 + w3 * f3;
            den += (w0 + w1) + (w2 + w3);
        }
        for (; j < m; ++j) {
            const int s = __shfl(myS, g * 16 + j, 64);
            float ev = es2[s] + ed;
            ev = ev > 0.f ? ev : NEG_SLOPE * ev;
            const float w = __expf(ev);
            acc += w * __bfloat162float(h2b[(size_t)s * C + c]);
            den += w;
        }
    }
    float evs = es2[n] + ed;
    evs = evs > 0.f ? evs : NEG_SLOPE * evs;
    const float ws = __expf(evs);
    acc += ws * __bfloat162float(h2b[(size_t)n * C + c]);
    den += ws;
    const float v = acc / den;
    float mx = v;
#pragma unroll
    for (int off = 1; off < 16; off <<= 1) mx = fmaxf(mx, __shfl_xor(mx, off, 64));
    float se = __expf(v - mx);
#pragma unroll
    for (int off = 1; off < 16; off <<= 1) se += __shfl_xor(se, off, 64);
    out[(size_t)n * C + c] = v - mx - __logf(se);
}

extern "C" void kernel_launch(void* const* d_in, const int* in_sizes, int n_in,
                              void* d_out, int out_size, void* d_ws, size_t ws_size,
                              hipStream_t stream) {
    const float* x   = (const float*)d_in[0];
    const int*   ei  = (const int*)d_in[1];
    const float* W1  = (const float*)d_in[2];
    const float* a1s = (const float*)d_in[3];
    const float* a1d = (const float*)d_in[4];
    const float* W2  = (const float*)d_in[5];
    const float* a2s = (const float*)d_in[6];
    const float* a2d = (const float*)d_in[7];
    float* out = (float*)d_out;

    const int n_nodes = in_sizes[0] / F_IN;   // 100000
    const int n_edges = in_sizes[1] / 2;      // 1600000
    const int* src = ei;
    const int* dst = ei + n_edges;
    const int n_scan_blocks = (n_nodes + SCAN_CHUNK - 1) / SCAN_CHUNK;
    const int nb = (n_nodes + (1 << BUCKET_SHIFT) - 1) >> BUCKET_SHIFT;   // 782

    // workspace layout
    float* fws = (float*)d_ws;
    float* es1 = fws;                              // N*8
    float* ed1 = es1 + (size_t)n_nodes * H1;       // N*8
    float* h1  = ed1 + (size_t)n_nodes * H1;       // N*64
    float* es2 = h1  + (size_t)n_nodes * F_MID;    // N
    float* ed2 = es2 + n_nodes;                    // N
    __hip_bfloat16* h1b = (__hip_bfloat16*)(ed2 + n_nodes);   // N*64 bf16
    __hip_bfloat16* h2b = h1b + (size_t)n_nodes * F_MID;      // N*16 bf16
    __hip_bfloat16* w1t = h2b + (size_t)n_nodes * C;          // 64*512 bf16
    int* iws        = (int*)(w1t + F_IN * F_MID);
    int* counts     = iws;                         // N       (zeroed)
    int* gcur       = counts + n_nodes;            // NB_MAX  (zeroed, contiguous w/ counts)
    int* row_start  = gcur + NB_MAX;               // N+1
    int* cursor     = row_start + n_nodes + 1;     // N
    int* sorted_src = cursor + n_nodes;            // E
    int* block_sums = sorted_src + n_edges;        // 256
    int* block_offs = block_sums + 256;            // 256
    int2* bucketed  = (int2*)(((uintptr_t)(block_offs + 256) + 15) & ~(uintptr_t)15);  // NB_MAX*3072 int2

    hipMemsetAsync(counts, 0, ((size_t)n_nodes + NB_MAX) * sizeof(int), stream);

    // bucketed counting-sort CSR build (shared by both layers)
    k_bin<<<(n_edges + BIN_CHUNK - 1) / BIN_CHUNK, 256, 0, stream>>>(src, dst, gcur, bucketed, n_edges, nb);
    k_bhist<<<nb, 256, 0, stream>>>(gcur, bucketed, counts, n_nodes);
    k_scan_reduce<<<n_scan_blocks, 256, 0, stream>>>(counts, block_sums, n_nodes);
    k_scan_sums<<<1, 256, 0, stream>>>(block_sums, block_offs, &row_start[n_nodes], n_scan_blocks);
    k_scan_apply<<<n_scan_blocks, 256, 0, stream>>>(counts, block_offs, row_start, cursor, n_nodes);
    k_bsort<<<nb, 256, 0, stream>>>(gcur, bucketed, cursor, sorted_src);

    // Layer 1
    k_w1t<<<(F_IN * F_MID) / 256, 256, 0, stream>>>(W1, w1t);
    k_gemm1<<<(n_nodes + 63) / 64, 256, 0, stream>>>(x, w1t, a1s, a1d, h1b, es1, ed1, n_nodes);
    k_gather1<<<(n_nodes + 3) / 4, 256, 0, stream>>>(row_start, sorted_src, h1b, es1, ed1, h1, n_nodes);

    // Layer 2
    k_gemm2<<<(n_nodes + 15) / 16, 256, 0, stream>>>(h1, W2, a2s, a2d, h2b, es2, ed2, n_nodes);
    k_gather2<<<(n_nodes + 15) / 16, 256, 0, stream>>>(row_start, sorted_src, h2b, es2, ed2, out, n_nodes);
}